// Round 6
// baseline (332.921 us; speedup 1.0000x reference)
//
#include <hip/hip_runtime.h>
#include <stdint.h>
#include <math.h>

#define EPS_C 0.01f
#define THRESH 0.8f

constexpr int Nn = 8192;
constexpr int Ff = 256;
constexpr int Ee = 262144;

__device__ __forceinline__ float b2f(unsigned short u) {
  union { uint32_t i; float f; } v; v.i = ((uint32_t)u) << 16; return v.f;
}
__device__ __forceinline__ unsigned short f2b(float f) {
  union { uint32_t i; float f; } v; v.f = f;
  uint32_t r = v.i + 0x7FFFu + ((v.i >> 16) & 1u);
  return (unsigned short)(r >> 16);
}

typedef __bf16 bf16x8 __attribute__((ext_vector_type(8)));
typedef float f32x4 __attribute__((ext_vector_type(4)));

// ---------- K3a: transpose+quantize z -> zT bf16 [256][8192]; colsum fused ----------
__global__ void k_transpose(const float* __restrict__ z, unsigned short* __restrict__ zT,
                            float* __restrict__ colsum) {
  __shared__ float Ls[64][65];
  int n0 = blockIdx.x * 64;
  int c0 = blockIdx.y * 64;
  int t = threadIdx.x;
  int r = t >> 4;        // 0..15
  int cq = t & 15;       // 0..15
#pragma unroll
  for (int i = 0; i < 4; ++i) {
    int row = r + 16 * i;
    float4 v = *(const float4*)(z + (size_t)(n0 + row) * Ff + c0 + cq * 4);
    Ls[row][cq * 4 + 0] = v.x;
    Ls[row][cq * 4 + 1] = v.y;
    Ls[row][cq * 4 + 2] = v.z;
    Ls[row][cq * 4 + 3] = v.w;
  }
  __syncthreads();
  // fused column-sum partial (64 rows of this tile)
  if (t < 64) {
    float s = 0.f;
#pragma unroll
    for (int rr = 0; rr < 64; ++rr) s += Ls[rr][t];
    atomicAdd(&colsum[c0 + t], s);
  }
  int cr = t >> 4;       // feature within tile
  int nq = t & 15;       // n-quad
#pragma unroll
  for (int i = 0; i < 4; ++i) {
    int c = cr + 16 * i;
    ushort4 o;
    o.x = f2b(Ls[nq * 4 + 0][c]);
    o.y = f2b(Ls[nq * 4 + 1][c]);
    o.z = f2b(Ls[nq * 4 + 2][c]);
    o.w = f2b(Ls[nq * 4 + 3][c]);
    *(ushort4*)(zT + (size_t)(c0 + c) * Nn + n0 + nq * 4) = o;
  }
}

// ---------- K3b: G = zT @ zT^T via MFMA, LDS-free direct-fragment loads ----------
__global__ __launch_bounds__(256) void k_covg(const unsigned short* __restrict__ zT,
                                              float* __restrict__ covp) {
  int bx = blockIdx.x, by = blockIdx.y, p = blockIdx.z;
  int t = threadIdx.x;
  int lane = t & 63, wv = t >> 6;
  int wr = wv >> 1, wc = wv & 1;
  int quad = lane >> 4, l15 = lane & 15;
  int a0 = by * 128, b0 = bx * 128;
  const unsigned short* Ab = zT + (size_t)(a0 + wr * 64 + l15) * Nn;
  const unsigned short* Bb = zT + (size_t)(b0 + wc * 64 + l15) * Nn;

  f32x4 acc[4][4];
#pragma unroll
  for (int i = 0; i < 4; ++i)
#pragma unroll
    for (int j = 0; j < 4; ++j) acc[i][j] = (f32x4){0.f, 0.f, 0.f, 0.f};

#pragma unroll 4
  for (int ks = 0; ks < 16; ++ks) {        // K-chunk of 512 per partial p
    int koff = p * 512 + ks * 32 + quad * 8;
    bf16x8 afr[4], bfr[4];
#pragma unroll
    for (int mt = 0; mt < 4; ++mt)
      afr[mt] = *(const bf16x8*)(Ab + (size_t)mt * 16 * Nn + koff);
#pragma unroll
    for (int nt = 0; nt < 4; ++nt)
      bfr[nt] = *(const bf16x8*)(Bb + (size_t)nt * 16 * Nn + koff);
#pragma unroll
    for (int mt = 0; mt < 4; ++mt)
#pragma unroll
      for (int nt = 0; nt < 4; ++nt)
        acc[mt][nt] = __builtin_amdgcn_mfma_f32_16x16x32_bf16(afr[mt], bfr[nt],
                                                              acc[mt][nt], 0, 0, 0);
  }

  float* outp = covp + (size_t)p * 65536;
#pragma unroll
  for (int mt = 0; mt < 4; ++mt)
#pragma unroll
    for (int r = 0; r < 4; ++r) {
      int a = a0 + wr * 64 + mt * 16 + quad * 4 + r;
#pragma unroll
      for (int nt = 0; nt < 4; ++nt) {
        int b = b0 + wc * 64 + nt * 16 + l15;
        outp[(size_t)a * Ff + b] = acc[mt][nt][r];
      }
    }
}

// ---------- K4: cor from partials (diag/std fused) ----------
__global__ void k_cor(const float* __restrict__ covp, const float* __restrict__ colsum,
                      float* __restrict__ cor) {
  __shared__ float sd[256];
  int a = blockIdx.x, b = threadIdx.x;
  float mb = colsum[b] * (1.f / 8192.f);
  float gb = 0.f;
#pragma unroll
  for (int p = 0; p < 16; ++p) gb += covp[(size_t)p * 65536 + b * 257];
  float sb = sqrtf(gb - 8192.f * mb * mb);
  sd[b] = sb;
  float g = 0.f;
#pragma unroll
  for (int p = 0; p < 16; ++p) g += covp[(size_t)p * 65536 + a * Ff + b];
  __syncthreads();
  float c = 0.f;
  if (a != b) {
    float ma = colsum[a] * (1.f / 8192.f);
    float cv = g - 8192.f * ma * mb;
    c = cv / (sd[a] * sb);
    if (c != c) c = 0.f;                 // nan_to_num
    c = fminf(1.f, fmaxf(-1.f, c));      // clip
  }
  cor[a * Ff + b] = c;
}

// ---------- K5: z2 = z + EPS*(w*zm)@cor, bf16; w + row norms fused ----------
__global__ __launch_bounds__(256) void k_z2(const float* __restrict__ z,
    const float* __restrict__ colsum, const int* __restrict__ k2u,
    const int* __restrict__ u2k, const float* __restrict__ cor,
    unsigned short* __restrict__ z2b, float* __restrict__ norms) {
  __shared__ float Wl[32 * 256];
  __shared__ float ws_[32];
  int t = threadIdx.x;
  int row0 = blockIdx.x * 32;
  if (t < 32) {
    int row = row0 + t;
    ws_[t] = powf(0.9f, (float)k2u[row]) + 1.f - powf(0.9f, (float)u2k[row]);
  }
  __syncthreads();
  float mt = colsum[t] * (1.f / 8192.f);
  for (int rr = 0; rr < 32; ++rr) {
    int row = row0 + rr;
    Wl[rr * 256 + t] = ws_[rr] * (z[(size_t)row * Ff + t] - mt);
  }
  __syncthreads();
  int tc = t & 63, tr = t >> 6;   // wave tr owns rows [tr*8, tr*8+8); lane == tc
  float acc[8][4];
#pragma unroll
  for (int i = 0; i < 8; ++i)
#pragma unroll
    for (int j = 0; j < 4; ++j) acc[i][j] = 0.f;
  const float* corc = cor + tc * 4;
  for (int k = 0; k < 256; ++k) {
    float4 c4 = *(const float4*)(corc + (size_t)k * 256);
#pragma unroll
    for (int rr = 0; rr < 8; ++rr) {
      float wv = Wl[(tr * 8 + rr) * 256 + k];
      acc[rr][0] = fmaf(wv, c4.x, acc[rr][0]);
      acc[rr][1] = fmaf(wv, c4.y, acc[rr][1]);
      acc[rr][2] = fmaf(wv, c4.z, acc[rr][2]);
      acc[rr][3] = fmaf(wv, c4.w, acc[rr][3]);
    }
  }
#pragma unroll
  for (int rr = 0; rr < 8; ++rr) {
    int row = row0 + tr * 8 + rr;
    float4 zv = *(const float4*)(z + (size_t)row * Ff + tc * 4);
    float x0 = zv.x + EPS_C * acc[rr][0];
    float x1 = zv.y + EPS_C * acc[rr][1];
    float x2 = zv.z + EPS_C * acc[rr][2];
    float x3 = zv.w + EPS_C * acc[rr][3];
    ushort4 o;
    o.x = f2b(x0); o.y = f2b(x1); o.z = f2b(x2); o.w = f2b(x3);
    *(ushort4*)(z2b + (size_t)row * Ff + tc * 4) = o;
    float s = x0 * x0 + x1 * x1 + x2 * x2 + x3 * x3;
#pragma unroll
    for (int m = 1; m < 64; m <<= 1) s += __shfl_xor(s, m);
    if (tc == 0) norms[row] = fmaxf(sqrtf(s), 1e-8f);
  }
}

// ---------- K7: adjacency bitmask ----------
__global__ void k_adj(const int* __restrict__ ei, const int* __restrict__ ej,
                      unsigned int* __restrict__ adj) {
  int e = blockIdx.x * 256 + threadIdx.x;
  unsigned int i = (unsigned int)ei[e], j = (unsigned int)ej[e];
  size_t b1 = (size_t)i * Nn + j;
  size_t b2 = (size_t)j * Nn + i;
  atomicOr(&adj[b1 >> 5], 1u << (b1 & 31));
  atomicOr(&adj[b2 >> 5], 1u << (b2 & 31));
}

// ---------- K8: per-edge cosine, batched ----------
__global__ __launch_bounds__(256) void k_edge(const int* __restrict__ ei,
                       const int* __restrict__ ej,
                       const unsigned short* __restrict__ z2b,
                       const float* __restrict__ norms,
                       float* __restrict__ scores, float* __restrict__ deg) {
  int t = threadIdx.x;
  int wv = t >> 6, lane = t & 63;
  int half = lane >> 5;
  int l32 = lane & 31;
  int gw = blockIdx.x * 4 + wv;
  int ebase = gw * 32;
#pragma unroll 2
  for (int it = 0; it < 16; ++it) {
    int e = ebase + it * 2 + half;
    int i = ei[e], j = ej[e];
    uint4 ua = *(const uint4*)(z2b + (size_t)i * Ff + l32 * 8);
    uint4 ub = *(const uint4*)(z2b + (size_t)j * Ff + l32 * 8);
    float d = 0.f;
    const uint32_t* pa = (const uint32_t*)&ua;
    const uint32_t* pb = (const uint32_t*)&ub;
#pragma unroll
    for (int q = 0; q < 4; ++q) {
      union { uint32_t u; float f; } alo, ahi, blo, bhi;
      alo.u = pa[q] << 16;  ahi.u = pa[q] & 0xffff0000u;
      blo.u = pb[q] << 16;  bhi.u = pb[q] & 0xffff0000u;
      d = fmaf(alo.f, blo.f, d);
      d = fmaf(ahi.f, bhi.f, d);
    }
#pragma unroll
    for (int m = 1; m < 32; m <<= 1) d += __shfl_xor(d, m);
    if (l32 == 0) {
      float sim = d / (norms[i] * norms[j]);
      atomicAdd(&scores[i], sim);
      atomicAdd(&deg[i], 1.f);
    }
  }
}

// ---------- K10: fused penalty GEMM — LDS-free, barrier-free direct-fragment loads ----------
__global__ __launch_bounds__(256) void k_penalty(const unsigned short* __restrict__ z2b,
    const unsigned int* __restrict__ adj, double* __restrict__ psum) {
  // triangular decode: 2080 blocks -> (br, bc), br <= bc
  int tb = blockIdx.x;
  int br = (int)(64.5 - sqrt(64.5 * 64.5 - 2.0 * (double)tb));
  while ((br + 1) * 64 - ((br + 1) * br) / 2 <= tb) ++br;
  while (br * 64 - (br * (br - 1)) / 2 > tb) --br;
  int bc = br + (tb - (br * 64 - (br * (br - 1)) / 2));

  int t = threadIdx.x;
  int lane = t & 63;
  int wv = t >> 6;
  int wr = wv >> 1, wc = wv & 1;             // 2x2 waves, each 64x64
  int quad = lane >> 4;
  int l15 = lane & 15;
  int arow0 = br * 128, brow0 = bc * 128;
  const unsigned short* Ab = z2b + (size_t)(arow0 + wr * 64 + l15) * Ff;
  const unsigned short* Bb = z2b + (size_t)(brow0 + wc * 64 + l15) * Ff;

  f32x4 acc[4][4];
#pragma unroll
  for (int i = 0; i < 4; ++i)
#pragma unroll
    for (int j = 0; j < 4; ++j) acc[i][j] = (f32x4){0.f, 0.f, 0.f, 0.f};

#pragma unroll
  for (int ks = 0; ks < 8; ++ks) {           // K = 256 = 8 x 32
    int koff = ks * 32 + quad * 8;           // lane's 8 contiguous bf16
    bf16x8 afr[4], bfr[4];
#pragma unroll
    for (int mt = 0; mt < 4; ++mt)
      afr[mt] = *(const bf16x8*)(Ab + (size_t)mt * 16 * Ff + koff);
#pragma unroll
    for (int nt = 0; nt < 4; ++nt)
      bfr[nt] = *(const bf16x8*)(Bb + (size_t)nt * 16 * Ff + koff);
#pragma unroll
    for (int mt = 0; mt < 4; ++mt)
#pragma unroll
      for (int nt = 0; nt < 4; ++nt)
        acc[mt][nt] = __builtin_amdgcn_mfma_f32_16x16x32_bf16(afr[mt], bfr[nt],
                                                              acc[mt][nt], 0, 0, 0);
  }

  // epilogue: masked thresholded sum with symmetry weights
  float local = 0.f;
  int a_base = arow0 + wr * 64;
  int b_base = brow0 + wc * 64;              // 64-aligned
#pragma unroll
  for (int mt = 0; mt < 4; ++mt) {
#pragma unroll
    for (int r = 0; r < 4; ++r) {
      int a = a_base + mt * 16 + quad * 4 + r;
      uint64_t bits = *(const uint64_t*)(adj + (size_t)a * 256 + (b_base >> 5));
#pragma unroll
      for (int nt = 0; nt < 4; ++nt) {
        float v = acc[mt][nt][r];
        int boff = nt * 16 + l15;
        bool conn = (bits >> boff) & 1ull;
        float wgt;
        if (br != bc) wgt = 2.f;
        else {
          int b = b_base + boff;
          wgt = (a < b) ? 2.f : (a == b ? 1.f : 0.f);
        }
        if (!conn && v > THRESH) local += wgt * v;
      }
    }
  }
#pragma unroll
  for (int m = 1; m < 64; m <<= 1) local += __shfl_xor(local, m);
  if (lane == 0) atomicAdd(psum, (double)local);   // one fp64 atomic per wave
}

// ---------- K11: homophily reduce + combine ----------
__global__ void k_final(const float* __restrict__ scores, const float* __restrict__ deg,
                        const double* __restrict__ psum, float* __restrict__ out) {
  __shared__ float red[4];
  int t = threadIdx.x;
  float acc = 0.f;
#pragma unroll 4
  for (int it = 0; it < 32; ++it) {
    int n = it * 256 + t;
    float dg = deg[n];
    acc += scores[n] / (dg == 0.f ? 1.f : dg);
  }
#pragma unroll
  for (int m = 1; m < 64; m <<= 1) acc += __shfl_xor(acc, m);
  if ((t & 63) == 0) red[t >> 6] = acc;
  __syncthreads();
  if (t == 0) {
    double h = -(double)(red[0] + red[1] + red[2] + red[3]) / 8192.0;
    double p = (*psum) / (8192.0 * 8192.0);
    out[0] = (float)(h + p);
  }
}

extern "C" void kernel_launch(void* const* d_in, const int* in_sizes, int n_in,
                              void* d_out, int out_size, void* d_ws, size_t ws_size,
                              hipStream_t stream) {
  const float* z = (const float*)d_in[0];
  // d_in[1] = x_hat (unused by the reference)
  const int* ei = (const int*)d_in[2];
  const int* ej = ei + Ee;
  const int* k2u = (const int*)d_in[3];
  const int* u2k = (const int*)d_in[4];

  char* ws = (char*)d_ws;
  // zeroed region: [0, ZERO_BYTES)
  unsigned int* adj = (unsigned int*)(ws);               // 8 MiB
  float* colsum     = (float*)(ws + 8388608);            // 1 KiB
  float* scores     = (float*)(ws + 8389632);            // 32 KiB
  float* deg        = (float*)(ws + 8422400);            // 32 KiB
  double* psum      = (double*)(ws + 8455168);           // 8 B
  const size_t ZERO_BYTES = 8455176;
  // non-zeroed scratch
  float* covp       = (float*)(ws + 8455296);            // 16 x 256 KiB = 4 MiB
  unsigned short* zT  = (unsigned short*)(ws + 12649600); // 4 MiB
  unsigned short* z2b = (unsigned short*)(ws + 16843904); // 4 MiB
  float* cor        = (float*)(ws + 21038208);           // 256 KiB
  float* norms      = (float*)(ws + 21300352);           // 32 KiB

  hipMemsetAsync(d_ws, 0, ZERO_BYTES, stream);
  k_adj<<<1024, 256, 0, stream>>>(ei, ej, adj);
  k_transpose<<<dim3(128, 4), 256, 0, stream>>>(z, zT, colsum);
  k_covg<<<dim3(2, 2, 16), 256, 0, stream>>>(zT, covp);
  k_cor<<<256, 256, 0, stream>>>(covp, colsum, cor);
  k_z2<<<256, 256, 0, stream>>>(z, colsum, k2u, u2k, cor, z2b, norms);
  k_edge<<<2048, 256, 0, stream>>>(ei, ej, z2b, norms, scores, deg);
  k_penalty<<<2080, 256, 0, stream>>>(z2b, adj, psum);
  k_final<<<1, 256, 0, stream>>>(scores, deg, psum, (float*)d_out);
}

// Round 7
// 297.925 us; speedup vs baseline: 1.1175x; 1.1175x over previous
//
#include <hip/hip_runtime.h>
#include <stdint.h>
#include <math.h>

#define EPS_C 0.01f
#define THRESH 0.8f

constexpr int Nn = 8192;
constexpr int Ff = 256;
constexpr int Ee = 262144;

__device__ __forceinline__ float b2f(unsigned short u) {
  union { uint32_t i; float f; } v; v.i = ((uint32_t)u) << 16; return v.f;
}
__device__ __forceinline__ unsigned short f2b(float f) {
  union { uint32_t i; float f; } v; v.f = f;
  uint32_t r = v.i + 0x7FFFu + ((v.i >> 16) & 1u);
  return (unsigned short)(r >> 16);
}

typedef __bf16 bf16x8 __attribute__((ext_vector_type(8)));
typedef float f32x4 __attribute__((ext_vector_type(4)));

// ---------- K3a: transpose+quantize z -> zT bf16 [256][8192]; colsum fused ----------
__global__ void k_transpose(const float* __restrict__ z, unsigned short* __restrict__ zT,
                            float* __restrict__ colsum) {
  __shared__ float Ls[64][65];
  int n0 = blockIdx.x * 64;
  int c0 = blockIdx.y * 64;
  int t = threadIdx.x;
  int r = t >> 4;        // 0..15
  int cq = t & 15;       // 0..15
#pragma unroll
  for (int i = 0; i < 4; ++i) {
    int row = r + 16 * i;
    float4 v = *(const float4*)(z + (size_t)(n0 + row) * Ff + c0 + cq * 4);
    Ls[row][cq * 4 + 0] = v.x;
    Ls[row][cq * 4 + 1] = v.y;
    Ls[row][cq * 4 + 2] = v.z;
    Ls[row][cq * 4 + 3] = v.w;
  }
  __syncthreads();
  // fused column-sum partial (64 rows of this tile)
  if (t < 64) {
    float s = 0.f;
#pragma unroll
    for (int rr = 0; rr < 64; ++rr) s += Ls[rr][t];
    atomicAdd(&colsum[c0 + t], s);
  }
  int cr = t >> 4;       // feature within tile
  int nq = t & 15;       // n-quad
#pragma unroll
  for (int i = 0; i < 4; ++i) {
    int c = cr + 16 * i;
    ushort4 o;
    o.x = f2b(Ls[nq * 4 + 0][c]);
    o.y = f2b(Ls[nq * 4 + 1][c]);
    o.z = f2b(Ls[nq * 4 + 2][c]);
    o.w = f2b(Ls[nq * 4 + 3][c]);
    *(ushort4*)(zT + (size_t)(c0 + c) * Nn + n0 + nq * 4) = o;
  }
}

// ---------- K3b: G = zT @ zT^T via MFMA, split-K=16 partials (LDS-staged) ----------
__global__ __launch_bounds__(256, 2) void k_covg(const unsigned short* __restrict__ zT,
                                                 float* __restrict__ covp) {
  int bx = blockIdx.x, by = blockIdx.y, p = blockIdx.z;
  __shared__ __align__(16) unsigned short As[128 * 64];
  __shared__ __align__(16) unsigned short Bs[128 * 64];
  int t = threadIdx.x;
  int lane = t & 63, wv = t >> 6;
  int wr = wv >> 1, wc = wv & 1;
  int quad = lane >> 4, l15 = lane & 15;
  int a0 = by * 128, b0 = bx * 128;

  f32x4 acc[4][4];
#pragma unroll
  for (int i = 0; i < 4; ++i)
#pragma unroll
    for (int j = 0; j < 4; ++j) acc[i][j] = (f32x4){0.f, 0.f, 0.f, 0.f};

  for (int kk = 0; kk < 8; ++kk) {
    int k0 = p * 512 + kk * 64;
#pragma unroll
    for (int it = 0; it < 4; ++it) {
      int s = it * 256 + t;
      int r = s >> 3;
      int g = (s & 7) ^ (r & 7);
      const unsigned short* ga = zT + (size_t)(a0 + r) * Nn + k0 + g * 8;
      const unsigned short* gb = zT + (size_t)(b0 + r) * Nn + k0 + g * 8;
      __builtin_amdgcn_global_load_lds((const __attribute__((address_space(1))) void*)ga,
                                       (__attribute__((address_space(3))) void*)(As + s * 8),
                                       16, 0, 0);
      __builtin_amdgcn_global_load_lds((const __attribute__((address_space(1))) void*)gb,
                                       (__attribute__((address_space(3))) void*)(Bs + s * 8),
                                       16, 0, 0);
    }
    __syncthreads();
#pragma unroll
    for (int kc = 0; kc < 2; ++kc) {
      bf16x8 afr[4], bfr[4];
#pragma unroll
      for (int mt = 0; mt < 4; ++mt) {
        int rA = wr * 64 + mt * 16 + l15;
        int g = kc * 4 + quad;
        int gl = g ^ (rA & 7);
        afr[mt] = *(const bf16x8*)(As + ((size_t)rA * 8 + gl) * 8);
      }
#pragma unroll
      for (int nt = 0; nt < 4; ++nt) {
        int rB = wc * 64 + nt * 16 + l15;
        int g = kc * 4 + quad;
        int gl = g ^ (rB & 7);
        bfr[nt] = *(const bf16x8*)(Bs + ((size_t)rB * 8 + gl) * 8);
      }
#pragma unroll
      for (int mt = 0; mt < 4; ++mt)
#pragma unroll
        for (int nt = 0; nt < 4; ++nt)
          acc[mt][nt] = __builtin_amdgcn_mfma_f32_16x16x32_bf16(afr[mt], bfr[nt],
                                                                acc[mt][nt], 0, 0, 0);
    }
    __syncthreads();
  }

  float* outp = covp + (size_t)p * 65536;
#pragma unroll
  for (int mt = 0; mt < 4; ++mt)
#pragma unroll
    for (int r = 0; r < 4; ++r) {
      int a = a0 + wr * 64 + mt * 16 + quad * 4 + r;
#pragma unroll
      for (int nt = 0; nt < 4; ++nt) {
        int b = b0 + wc * 64 + nt * 16 + l15;
        outp[(size_t)a * Ff + b] = acc[mt][nt][r];
      }
    }
}

// ---------- K4: cor from partials (diag/std fused) ----------
__global__ void k_cor(const float* __restrict__ covp, const float* __restrict__ colsum,
                      float* __restrict__ cor) {
  __shared__ float sd[256];
  int a = blockIdx.x, b = threadIdx.x;
  float mb = colsum[b] * (1.f / 8192.f);
  float gb = 0.f;
#pragma unroll
  for (int p = 0; p < 16; ++p) gb += covp[(size_t)p * 65536 + b * 257];
  float sb = sqrtf(gb - 8192.f * mb * mb);
  sd[b] = sb;
  float g = 0.f;
#pragma unroll
  for (int p = 0; p < 16; ++p) g += covp[(size_t)p * 65536 + a * Ff + b];
  __syncthreads();
  float c = 0.f;
  if (a != b) {
    float ma = colsum[a] * (1.f / 8192.f);
    float cv = g - 8192.f * ma * mb;
    c = cv / (sd[a] * sb);
    if (c != c) c = 0.f;                 // nan_to_num
    c = fminf(1.f, fmaxf(-1.f, c));      // clip
  }
  cor[a * Ff + b] = c;
}

// ---------- K5: z2 = z + EPS*(w*zm)@cor, bf16; w + row norms fused ----------
__global__ __launch_bounds__(256) void k_z2(const float* __restrict__ z,
    const float* __restrict__ colsum, const int* __restrict__ k2u,
    const int* __restrict__ u2k, const float* __restrict__ cor,
    unsigned short* __restrict__ z2b, float* __restrict__ norms) {
  __shared__ float Wl[32 * 256];
  __shared__ float ws_[32];
  int t = threadIdx.x;
  int row0 = blockIdx.x * 32;
  if (t < 32) {
    int row = row0 + t;
    ws_[t] = powf(0.9f, (float)k2u[row]) + 1.f - powf(0.9f, (float)u2k[row]);
  }
  __syncthreads();
  float mt = colsum[t] * (1.f / 8192.f);
  for (int rr = 0; rr < 32; ++rr) {
    int row = row0 + rr;
    Wl[rr * 256 + t] = ws_[rr] * (z[(size_t)row * Ff + t] - mt);
  }
  __syncthreads();
  int tc = t & 63, tr = t >> 6;   // wave tr owns rows [tr*8, tr*8+8); lane == tc
  float acc[8][4];
#pragma unroll
  for (int i = 0; i < 8; ++i)
#pragma unroll
    for (int j = 0; j < 4; ++j) acc[i][j] = 0.f;
  const float* corc = cor + tc * 4;
  for (int k = 0; k < 256; ++k) {
    float4 c4 = *(const float4*)(corc + (size_t)k * 256);
#pragma unroll
    for (int rr = 0; rr < 8; ++rr) {
      float wv = Wl[(tr * 8 + rr) * 256 + k];
      acc[rr][0] = fmaf(wv, c4.x, acc[rr][0]);
      acc[rr][1] = fmaf(wv, c4.y, acc[rr][1]);
      acc[rr][2] = fmaf(wv, c4.z, acc[rr][2]);
      acc[rr][3] = fmaf(wv, c4.w, acc[rr][3]);
    }
  }
#pragma unroll
  for (int rr = 0; rr < 8; ++rr) {
    int row = row0 + tr * 8 + rr;
    float4 zv = *(const float4*)(z + (size_t)row * Ff + tc * 4);
    float x0 = zv.x + EPS_C * acc[rr][0];
    float x1 = zv.y + EPS_C * acc[rr][1];
    float x2 = zv.z + EPS_C * acc[rr][2];
    float x3 = zv.w + EPS_C * acc[rr][3];
    ushort4 o;
    o.x = f2b(x0); o.y = f2b(x1); o.z = f2b(x2); o.w = f2b(x3);
    *(ushort4*)(z2b + (size_t)row * Ff + tc * 4) = o;
    float s = x0 * x0 + x1 * x1 + x2 * x2 + x3 * x3;
#pragma unroll
    for (int m = 1; m < 64; m <<= 1) s += __shfl_xor(s, m);
    if (tc == 0) norms[row] = fmaxf(sqrtf(s), 1e-8f);
  }
}

// ---------- K7: adjacency bitmask ----------
__global__ void k_adj(const int* __restrict__ ei, const int* __restrict__ ej,
                      unsigned int* __restrict__ adj) {
  int e = blockIdx.x * 256 + threadIdx.x;
  unsigned int i = (unsigned int)ei[e], j = (unsigned int)ej[e];
  size_t b1 = (size_t)i * Nn + j;
  size_t b2 = (size_t)j * Nn + i;
  atomicOr(&adj[b1 >> 5], 1u << (b1 & 31));
  atomicOr(&adj[b2 >> 5], 1u << (b2 & 31));
}

// ---------- K8: per-edge cosine, batched ----------
__global__ __launch_bounds__(256) void k_edge(const int* __restrict__ ei,
                       const int* __restrict__ ej,
                       const unsigned short* __restrict__ z2b,
                       const float* __restrict__ norms,
                       float* __restrict__ scores, float* __restrict__ deg) {
  int t = threadIdx.x;
  int wv = t >> 6, lane = t & 63;
  int half = lane >> 5;
  int l32 = lane & 31;
  int gw = blockIdx.x * 4 + wv;
  int ebase = gw * 32;
#pragma unroll 2
  for (int it = 0; it < 16; ++it) {
    int e = ebase + it * 2 + half;
    int i = ei[e], j = ej[e];
    uint4 ua = *(const uint4*)(z2b + (size_t)i * Ff + l32 * 8);
    uint4 ub = *(const uint4*)(z2b + (size_t)j * Ff + l32 * 8);
    float d = 0.f;
    const uint32_t* pa = (const uint32_t*)&ua;
    const uint32_t* pb = (const uint32_t*)&ub;
#pragma unroll
    for (int q = 0; q < 4; ++q) {
      union { uint32_t u; float f; } alo, ahi, blo, bhi;
      alo.u = pa[q] << 16;  ahi.u = pa[q] & 0xffff0000u;
      blo.u = pb[q] << 16;  bhi.u = pb[q] & 0xffff0000u;
      d = fmaf(alo.f, blo.f, d);
      d = fmaf(ahi.f, bhi.f, d);
    }
#pragma unroll
    for (int m = 1; m < 32; m <<= 1) d += __shfl_xor(d, m);
    if (l32 == 0) {
      float sim = d / (norms[i] * norms[j]);
      atomicAdd(&scores[i], sim);
      atomicAdd(&deg[i], 1.f);
    }
  }
}

// ---------- K10: fused penalty GEMM — pipelined + adj prefetched into registers ----------
__global__ __launch_bounds__(256, 2) void k_penalty(const unsigned short* __restrict__ z2b,
    const unsigned int* __restrict__ adj, double* __restrict__ psum) {
  // triangular decode: 2080 blocks -> (br, bc), br <= bc
  int tb = blockIdx.x;
  int br = (int)(64.5 - sqrt(64.5 * 64.5 - 2.0 * (double)tb));
  while ((br + 1) * 64 - ((br + 1) * br) / 2 <= tb) ++br;
  while (br * 64 - (br * (br - 1)) / 2 > tb) --br;
  int bc = br + (tb - (br * 64 - (br * (br - 1)) / 2));

  __shared__ __align__(16) unsigned short LB[32768];  // 64 KB: 2 phase-buffers x (A 16KB + B 16KB)
  int t = threadIdx.x;
  int lane = t & 63;
  int wv = t >> 6;
  int wr = wv >> 1, wc = wv & 1;             // 2x2 waves, each 64x64
  int quad = lane >> 4;
  int l15 = lane & 15;
  int arow0 = br * 128, brow0 = bc * 128;
  int a_base = arow0 + wr * 64;
  int b_base = brow0 + wc * 64;              // 64-aligned

  f32x4 acc[4][4];
#pragma unroll
  for (int i = 0; i < 4; ++i)
#pragma unroll
    for (int j = 0; j < 4; ++j) acc[i][j] = (f32x4){0.f, 0.f, 0.f, 0.f};

  // stage phase p (64-wide K panel) into ping-pong buffer: 8 loads/thread
#define ISSUE_PHASE(p)                                                                   \
  {                                                                                      \
    unsigned short* buf = LB + ((p) & 1) * 16384;                                        \
    int k0 = (p) * 64;                                                                   \
    _Pragma("unroll")                                                                    \
    for (int it = 0; it < 4; ++it) {                                                     \
      int s = it * 256 + t;                                                              \
      int r = s >> 3;                                                                    \
      int g = (s & 7) ^ (r & 7);                                                         \
      const unsigned short* ga = z2b + (size_t)(arow0 + r) * Ff + k0 + g * 8;            \
      const unsigned short* gb = z2b + (size_t)(brow0 + r) * Ff + k0 + g * 8;            \
      __builtin_amdgcn_global_load_lds((const __attribute__((address_space(1))) void*)ga,\
                                       (__attribute__((address_space(3))) void*)(buf + s * 8),      \
                                       16, 0, 0);                                        \
      __builtin_amdgcn_global_load_lds((const __attribute__((address_space(1))) void*)gb,\
                                       (__attribute__((address_space(3))) void*)(buf + 8192 + s * 8),\
                                       16, 0, 0);                                        \
    }                                                                                    \
  }

  ISSUE_PHASE(0)
  ISSUE_PHASE(1)

  // prefetch adjacency words for the epilogue NOW — they ride behind phases 0-1 compute
  uint64_t bitsr[16];
#pragma unroll
  for (int mt = 0; mt < 4; ++mt)
#pragma unroll
    for (int r = 0; r < 4; ++r) {
      int a = a_base + mt * 16 + quad * 4 + r;
      bitsr[mt * 4 + r] = *(const uint64_t*)(adj + (size_t)a * 256 + (b_base >> 5));
    }
  __builtin_amdgcn_sched_barrier(0);   // pin: adj loads issued here, not sunk to epilogue

#pragma unroll
  for (int p = 0; p < 4; ++p) {
    // partial drains: adj's 16 loads are newer than phase p<2's staging
    if (p < 2)      __builtin_amdgcn_s_waitcnt(0x4F78);  // vmcnt(24)
    else if (p == 2) __builtin_amdgcn_s_waitcnt(0xF78);  // vmcnt(8)
    else             __builtin_amdgcn_s_waitcnt(0xF70);  // vmcnt(0)
    __builtin_amdgcn_s_barrier();
    const unsigned short* As = LB + (p & 1) * 16384;
    const unsigned short* Bs = As + 8192;
#pragma unroll
    for (int kc = 0; kc < 2; ++kc) {
      bf16x8 afr[4], bfr[4];
#pragma unroll
      for (int mt = 0; mt < 4; ++mt) {
        int rA = wr * 64 + mt * 16 + l15;
        int g = kc * 4 + quad;
        int gl = g ^ (rA & 7);
        afr[mt] = *(const bf16x8*)(As + ((size_t)rA * 8 + gl) * 8);
      }
#pragma unroll
      for (int nt = 0; nt < 4; ++nt) {
        int rB = wc * 64 + nt * 16 + l15;
        int g = kc * 4 + quad;
        int gl = g ^ (rB & 7);
        bfr[nt] = *(const bf16x8*)(Bs + ((size_t)rB * 8 + gl) * 8);
      }
#pragma unroll
      for (int mt = 0; mt < 4; ++mt)
#pragma unroll
        for (int nt = 0; nt < 4; ++nt)
          acc[mt][nt] = __builtin_amdgcn_mfma_f32_16x16x32_bf16(afr[mt], bfr[nt],
                                                                acc[mt][nt], 0, 0, 0);
    }
    __builtin_amdgcn_s_barrier();                   // all waves done reading buf[p&1]
    if (p < 2) ISSUE_PHASE(p + 2)                   // refill the buffer just freed
  }
#undef ISSUE_PHASE

  // epilogue: masked thresholded sum with symmetry weights (adj already in registers)
  float local = 0.f;
#pragma unroll
  for (int mt = 0; mt < 4; ++mt) {
#pragma unroll
    for (int r = 0; r < 4; ++r) {
      uint64_t bits = bitsr[mt * 4 + r];
      int a = a_base + mt * 16 + quad * 4 + r;
#pragma unroll
      for (int nt = 0; nt < 4; ++nt) {
        float v = acc[mt][nt][r];
        int boff = nt * 16 + l15;
        bool conn = (bits >> boff) & 1ull;
        float wgt;
        if (br != bc) wgt = 2.f;
        else {
          int b = b_base + boff;
          wgt = (a < b) ? 2.f : (a == b ? 1.f : 0.f);
        }
        if (!conn && v > THRESH) local += wgt * v;
      }
    }
  }
#pragma unroll
  for (int m = 1; m < 64; m <<= 1) local += __shfl_xor(local, m);
  if (lane == 0) atomicAdd(psum, (double)local);   // one fp64 atomic per wave
}

// ---------- K11: homophily reduce + combine ----------
__global__ void k_final(const float* __restrict__ scores, const float* __restrict__ deg,
                        const double* __restrict__ psum, float* __restrict__ out) {
  __shared__ float red[4];
  int t = threadIdx.x;
  float acc = 0.f;
#pragma unroll 4
  for (int it = 0; it < 32; ++it) {
    int n = it * 256 + t;
    float dg = deg[n];
    acc += scores[n] / (dg == 0.f ? 1.f : dg);
  }
#pragma unroll
  for (int m = 1; m < 64; m <<= 1) acc += __shfl_xor(acc, m);
  if ((t & 63) == 0) red[t >> 6] = acc;
  __syncthreads();
  if (t == 0) {
    double h = -(double)(red[0] + red[1] + red[2] + red[3]) / 8192.0;
    double p = (*psum) / (8192.0 * 8192.0);
    out[0] = (float)(h + p);
  }
}

extern "C" void kernel_launch(void* const* d_in, const int* in_sizes, int n_in,
                              void* d_out, int out_size, void* d_ws, size_t ws_size,
                              hipStream_t stream) {
  const float* z = (const float*)d_in[0];
  // d_in[1] = x_hat (unused by the reference)
  const int* ei = (const int*)d_in[2];
  const int* ej = ei + Ee;
  const int* k2u = (const int*)d_in[3];
  const int* u2k = (const int*)d_in[4];

  char* ws = (char*)d_ws;
  // zeroed region: [0, ZERO_BYTES)
  unsigned int* adj = (unsigned int*)(ws);               // 8 MiB
  float* colsum     = (float*)(ws + 8388608);            // 1 KiB
  float* scores     = (float*)(ws + 8389632);            // 32 KiB
  float* deg        = (float*)(ws + 8422400);            // 32 KiB
  double* psum      = (double*)(ws + 8455168);           // 8 B
  const size_t ZERO_BYTES = 8455176;
  // non-zeroed scratch
  float* covp       = (float*)(ws + 8455296);            // 16 x 256 KiB = 4 MiB
  unsigned short* zT  = (unsigned short*)(ws + 12649600); // 4 MiB
  unsigned short* z2b = (unsigned short*)(ws + 16843904); // 4 MiB
  float* cor        = (float*)(ws + 21038208);           // 256 KiB
  float* norms      = (float*)(ws + 21300352);           // 32 KiB

  hipMemsetAsync(d_ws, 0, ZERO_BYTES, stream);
  k_adj<<<1024, 256, 0, stream>>>(ei, ej, adj);
  k_transpose<<<dim3(128, 4), 256, 0, stream>>>(z, zT, colsum);
  k_covg<<<dim3(2, 2, 16), 256, 0, stream>>>(zT, covp);
  k_cor<<<256, 256, 0, stream>>>(covp, colsum, cor);
  k_z2<<<256, 256, 0, stream>>>(z, colsum, k2u, u2k, cor, z2b, norms);
  k_edge<<<2048, 256, 0, stream>>>(ei, ej, z2b, norms, scores, deg);
  k_penalty<<<2080, 256, 0, stream>>>(z2b, adj, psum);
  k_final<<<1, 256, 0, stream>>>(scores, deg, psum, (float*)d_out);
}

// Round 8
// 217.822 us; speedup vs baseline: 1.5284x; 1.3677x over previous
//
#include <hip/hip_runtime.h>
#include <stdint.h>
#include <math.h>

#define EPS_C 0.01f
#define THRESH 0.8f

constexpr int Nn = 8192;
constexpr int Ff = 256;
constexpr int Ee = 262144;

__device__ __forceinline__ float b2f(unsigned short u) {
  union { uint32_t i; float f; } v; v.i = ((uint32_t)u) << 16; return v.f;
}
__device__ __forceinline__ unsigned short f2b(float f) {
  union { uint32_t i; float f; } v; v.f = f;
  uint32_t r = v.i + 0x7FFFu + ((v.i >> 16) & 1u);
  return (unsigned short)(r >> 16);
}

typedef __bf16 bf16x8 __attribute__((ext_vector_type(8)));
typedef float f32x4 __attribute__((ext_vector_type(4)));

// ---------- K3a: transpose+quantize z -> zT bf16 [256][8192]; colsum fused ----------
__global__ void k_transpose(const float* __restrict__ z, unsigned short* __restrict__ zT,
                            float* __restrict__ colsum) {
  __shared__ float Ls[64][65];
  int n0 = blockIdx.x * 64;
  int c0 = blockIdx.y * 64;
  int t = threadIdx.x;
  int r = t >> 4;        // 0..15
  int cq = t & 15;       // 0..15
#pragma unroll
  for (int i = 0; i < 4; ++i) {
    int row = r + 16 * i;
    float4 v = *(const float4*)(z + (size_t)(n0 + row) * Ff + c0 + cq * 4);
    Ls[row][cq * 4 + 0] = v.x;
    Ls[row][cq * 4 + 1] = v.y;
    Ls[row][cq * 4 + 2] = v.z;
    Ls[row][cq * 4 + 3] = v.w;
  }
  __syncthreads();
  // fused column-sum partial (64 rows of this tile)
  if (t < 64) {
    float s = 0.f;
#pragma unroll
    for (int rr = 0; rr < 64; ++rr) s += Ls[rr][t];
    atomicAdd(&colsum[c0 + t], s);
  }
  int cr = t >> 4;       // feature within tile
  int nq = t & 15;       // n-quad
#pragma unroll
  for (int i = 0; i < 4; ++i) {
    int c = cr + 16 * i;
    ushort4 o;
    o.x = f2b(Ls[nq * 4 + 0][c]);
    o.y = f2b(Ls[nq * 4 + 1][c]);
    o.z = f2b(Ls[nq * 4 + 2][c]);
    o.w = f2b(Ls[nq * 4 + 3][c]);
    *(ushort4*)(zT + (size_t)(c0 + c) * Nn + n0 + nq * 4) = o;
  }
}

// ---------- K3b: G = zT @ zT^T via MFMA, split-K=16 partials (LDS-staged) ----------
__global__ __launch_bounds__(256, 2) void k_covg(const unsigned short* __restrict__ zT,
                                                 float* __restrict__ covp) {
  int bx = blockIdx.x, by = blockIdx.y, p = blockIdx.z;
  __shared__ __align__(16) unsigned short As[128 * 64];
  __shared__ __align__(16) unsigned short Bs[128 * 64];
  int t = threadIdx.x;
  int lane = t & 63, wv = t >> 6;
  int wr = wv >> 1, wc = wv & 1;
  int quad = lane >> 4, l15 = lane & 15;
  int a0 = by * 128, b0 = bx * 128;

  f32x4 acc[4][4];
#pragma unroll
  for (int i = 0; i < 4; ++i)
#pragma unroll
    for (int j = 0; j < 4; ++j) acc[i][j] = (f32x4){0.f, 0.f, 0.f, 0.f};

  for (int kk = 0; kk < 8; ++kk) {
    int k0 = p * 512 + kk * 64;
#pragma unroll
    for (int it = 0; it < 4; ++it) {
      int s = it * 256 + t;
      int r = s >> 3;
      int g = (s & 7) ^ (r & 7);
      const unsigned short* ga = zT + (size_t)(a0 + r) * Nn + k0 + g * 8;
      const unsigned short* gb = zT + (size_t)(b0 + r) * Nn + k0 + g * 8;
      __builtin_amdgcn_global_load_lds((const __attribute__((address_space(1))) void*)ga,
                                       (__attribute__((address_space(3))) void*)(As + s * 8),
                                       16, 0, 0);
      __builtin_amdgcn_global_load_lds((const __attribute__((address_space(1))) void*)gb,
                                       (__attribute__((address_space(3))) void*)(Bs + s * 8),
                                       16, 0, 0);
    }
    __syncthreads();
#pragma unroll
    for (int kc = 0; kc < 2; ++kc) {
      bf16x8 afr[4], bfr[4];
#pragma unroll
      for (int mt = 0; mt < 4; ++mt) {
        int rA = wr * 64 + mt * 16 + l15;
        int g = kc * 4 + quad;
        int gl = g ^ (rA & 7);
        afr[mt] = *(const bf16x8*)(As + ((size_t)rA * 8 + gl) * 8);
      }
#pragma unroll
      for (int nt = 0; nt < 4; ++nt) {
        int rB = wc * 64 + nt * 16 + l15;
        int g = kc * 4 + quad;
        int gl = g ^ (rB & 7);
        bfr[nt] = *(const bf16x8*)(Bs + ((size_t)rB * 8 + gl) * 8);
      }
#pragma unroll
      for (int mt = 0; mt < 4; ++mt)
#pragma unroll
        for (int nt = 0; nt < 4; ++nt)
          acc[mt][nt] = __builtin_amdgcn_mfma_f32_16x16x32_bf16(afr[mt], bfr[nt],
                                                                acc[mt][nt], 0, 0, 0);
    }
    __syncthreads();
  }

  float* outp = covp + (size_t)p * 65536;
#pragma unroll
  for (int mt = 0; mt < 4; ++mt)
#pragma unroll
    for (int r = 0; r < 4; ++r) {
      int a = a0 + wr * 64 + mt * 16 + quad * 4 + r;
#pragma unroll
      for (int nt = 0; nt < 4; ++nt) {
        int b = b0 + wc * 64 + nt * 16 + l15;
        outp[(size_t)a * Ff + b] = acc[mt][nt][r];
      }
    }
}

// ---------- K4: cor from partials (diag/std fused) ----------
__global__ void k_cor(const float* __restrict__ covp, const float* __restrict__ colsum,
                      float* __restrict__ cor) {
  __shared__ float sd[256];
  int a = blockIdx.x, b = threadIdx.x;
  float mb = colsum[b] * (1.f / 8192.f);
  float gb = 0.f;
#pragma unroll
  for (int p = 0; p < 16; ++p) gb += covp[(size_t)p * 65536 + b * 257];
  float sb = sqrtf(gb - 8192.f * mb * mb);
  sd[b] = sb;
  float g = 0.f;
#pragma unroll
  for (int p = 0; p < 16; ++p) g += covp[(size_t)p * 65536 + a * Ff + b];
  __syncthreads();
  float c = 0.f;
  if (a != b) {
    float ma = colsum[a] * (1.f / 8192.f);
    float cv = g - 8192.f * ma * mb;
    c = cv / (sd[a] * sb);
    if (c != c) c = 0.f;                 // nan_to_num
    c = fminf(1.f, fmaxf(-1.f, c));      // clip
  }
  cor[a * Ff + b] = c;
}

// ---------- K5: z2 = z + EPS*(w*zm)@cor, bf16; w + row norms fused ----------
__global__ __launch_bounds__(256) void k_z2(const float* __restrict__ z,
    const float* __restrict__ colsum, const int* __restrict__ k2u,
    const int* __restrict__ u2k, const float* __restrict__ cor,
    unsigned short* __restrict__ z2b, float* __restrict__ norms) {
  __shared__ float Wl[32 * 256];
  __shared__ float ws_[32];
  int t = threadIdx.x;
  int row0 = blockIdx.x * 32;
  if (t < 32) {
    int row = row0 + t;
    ws_[t] = powf(0.9f, (float)k2u[row]) + 1.f - powf(0.9f, (float)u2k[row]);
  }
  __syncthreads();
  float mt = colsum[t] * (1.f / 8192.f);
  for (int rr = 0; rr < 32; ++rr) {
    int row = row0 + rr;
    Wl[rr * 256 + t] = ws_[rr] * (z[(size_t)row * Ff + t] - mt);
  }
  __syncthreads();
  int tc = t & 63, tr = t >> 6;   // wave tr owns rows [tr*8, tr*8+8); lane == tc
  float acc[8][4];
#pragma unroll
  for (int i = 0; i < 8; ++i)
#pragma unroll
    for (int j = 0; j < 4; ++j) acc[i][j] = 0.f;
  const float* corc = cor + tc * 4;
  for (int k = 0; k < 256; ++k) {
    float4 c4 = *(const float4*)(corc + (size_t)k * 256);
#pragma unroll
    for (int rr = 0; rr < 8; ++rr) {
      float wv = Wl[(tr * 8 + rr) * 256 + k];
      acc[rr][0] = fmaf(wv, c4.x, acc[rr][0]);
      acc[rr][1] = fmaf(wv, c4.y, acc[rr][1]);
      acc[rr][2] = fmaf(wv, c4.z, acc[rr][2]);
      acc[rr][3] = fmaf(wv, c4.w, acc[rr][3]);
    }
  }
#pragma unroll
  for (int rr = 0; rr < 8; ++rr) {
    int row = row0 + tr * 8 + rr;
    float4 zv = *(const float4*)(z + (size_t)row * Ff + tc * 4);
    float x0 = zv.x + EPS_C * acc[rr][0];
    float x1 = zv.y + EPS_C * acc[rr][1];
    float x2 = zv.z + EPS_C * acc[rr][2];
    float x3 = zv.w + EPS_C * acc[rr][3];
    ushort4 o;
    o.x = f2b(x0); o.y = f2b(x1); o.z = f2b(x2); o.w = f2b(x3);
    *(ushort4*)(z2b + (size_t)row * Ff + tc * 4) = o;
    float s = x0 * x0 + x1 * x1 + x2 * x2 + x3 * x3;
#pragma unroll
    for (int m = 1; m < 64; m <<= 1) s += __shfl_xor(s, m);
    if (tc == 0) norms[row] = fmaxf(sqrtf(s), 1e-8f);
  }
}

// ---------- K7: adjacency bitmask ----------
__global__ void k_adj(const int* __restrict__ ei, const int* __restrict__ ej,
                      unsigned int* __restrict__ adj) {
  int e = blockIdx.x * 256 + threadIdx.x;
  unsigned int i = (unsigned int)ei[e], j = (unsigned int)ej[e];
  size_t b1 = (size_t)i * Nn + j;
  size_t b2 = (size_t)j * Nn + i;
  atomicOr(&adj[b1 >> 5], 1u << (b1 & 31));
  atomicOr(&adj[b2 >> 5], 1u << (b2 & 31));
}

// ---------- K8: per-edge cosine, batched ----------
__global__ __launch_bounds__(256) void k_edge(const int* __restrict__ ei,
                       const int* __restrict__ ej,
                       const unsigned short* __restrict__ z2b,
                       const float* __restrict__ norms,
                       float* __restrict__ scores, float* __restrict__ deg) {
  int t = threadIdx.x;
  int wv = t >> 6, lane = t & 63;
  int half = lane >> 5;
  int l32 = lane & 31;
  int gw = blockIdx.x * 4 + wv;
  int ebase = gw * 32;
#pragma unroll 2
  for (int it = 0; it < 16; ++it) {
    int e = ebase + it * 2 + half;
    int i = ei[e], j = ej[e];
    uint4 ua = *(const uint4*)(z2b + (size_t)i * Ff + l32 * 8);
    uint4 ub = *(const uint4*)(z2b + (size_t)j * Ff + l32 * 8);
    float d = 0.f;
    const uint32_t* pa = (const uint32_t*)&ua;
    const uint32_t* pb = (const uint32_t*)&ub;
#pragma unroll
    for (int q = 0; q < 4; ++q) {
      union { uint32_t u; float f; } alo, ahi, blo, bhi;
      alo.u = pa[q] << 16;  ahi.u = pa[q] & 0xffff0000u;
      blo.u = pb[q] << 16;  bhi.u = pb[q] & 0xffff0000u;
      d = fmaf(alo.f, blo.f, d);
      d = fmaf(ahi.f, bhi.f, d);
    }
#pragma unroll
    for (int m = 1; m < 32; m <<= 1) d += __shfl_xor(d, m);
    if (l32 == 0) {
      float sim = d / (norms[i] * norms[j]);
      atomicAdd(&scores[i], sim);
      atomicAdd(&deg[i], 1.f);
    }
  }
}

// ---------- K10: fused penalty GEMM — pipelined, NO atomics (per-block partial) ----------
__global__ __launch_bounds__(256, 2) void k_penalty(const unsigned short* __restrict__ z2b,
    const unsigned int* __restrict__ adj, float* __restrict__ pp) {
  // triangular decode: 2080 blocks -> (br, bc), br <= bc
  int tb = blockIdx.x;
  int br = (int)(64.5 - sqrt(64.5 * 64.5 - 2.0 * (double)tb));
  while ((br + 1) * 64 - ((br + 1) * br) / 2 <= tb) ++br;
  while (br * 64 - (br * (br - 1)) / 2 > tb) --br;
  int bc = br + (tb - (br * 64 - (br * (br - 1)) / 2));

  __shared__ __align__(16) unsigned short LB[32768];  // 64 KB: 2 phase-buffers x (A 16KB + B 16KB)
  int t = threadIdx.x;
  int lane = t & 63;
  int wv = t >> 6;
  int wr = wv >> 1, wc = wv & 1;             // 2x2 waves, each 64x64
  int quad = lane >> 4;
  int l15 = lane & 15;
  int arow0 = br * 128, brow0 = bc * 128;

  f32x4 acc[4][4];
#pragma unroll
  for (int i = 0; i < 4; ++i)
#pragma unroll
    for (int j = 0; j < 4; ++j) acc[i][j] = (f32x4){0.f, 0.f, 0.f, 0.f};

  // stage phase p (64-wide K panel) into ping-pong buffer: 8 loads/thread
#define ISSUE_PHASE(p)                                                                   \
  {                                                                                      \
    unsigned short* buf = LB + ((p) & 1) * 16384;                                        \
    int k0 = (p) * 64;                                                                   \
    _Pragma("unroll")                                                                    \
    for (int it = 0; it < 4; ++it) {                                                     \
      int s = it * 256 + t;                                                              \
      int r = s >> 3;                                                                    \
      int g = (s & 7) ^ (r & 7);                                                         \
      const unsigned short* ga = z2b + (size_t)(arow0 + r) * Ff + k0 + g * 8;            \
      const unsigned short* gb = z2b + (size_t)(brow0 + r) * Ff + k0 + g * 8;            \
      __builtin_amdgcn_global_load_lds((const __attribute__((address_space(1))) void*)ga,\
                                       (__attribute__((address_space(3))) void*)(buf + s * 8),      \
                                       16, 0, 0);                                        \
      __builtin_amdgcn_global_load_lds((const __attribute__((address_space(1))) void*)gb,\
                                       (__attribute__((address_space(3))) void*)(buf + 8192 + s * 8),\
                                       16, 0, 0);                                        \
    }                                                                                    \
  }

  ISSUE_PHASE(0)
  ISSUE_PHASE(1)
#pragma unroll
  for (int p = 0; p < 4; ++p) {
    if (p < 3) __builtin_amdgcn_s_waitcnt(0xF78);   // vmcnt(8): this phase's loads done, next in flight
    else       __builtin_amdgcn_s_waitcnt(0xF70);   // vmcnt(0)
    __builtin_amdgcn_s_barrier();
    const unsigned short* As = LB + (p & 1) * 16384;
    const unsigned short* Bs = As + 8192;
#pragma unroll
    for (int kc = 0; kc < 2; ++kc) {
      bf16x8 afr[4], bfr[4];
#pragma unroll
      for (int mt = 0; mt < 4; ++mt) {
        int rA = wr * 64 + mt * 16 + l15;
        int g = kc * 4 + quad;
        int gl = g ^ (rA & 7);
        afr[mt] = *(const bf16x8*)(As + ((size_t)rA * 8 + gl) * 8);
      }
#pragma unroll
      for (int nt = 0; nt < 4; ++nt) {
        int rB = wc * 64 + nt * 16 + l15;
        int g = kc * 4 + quad;
        int gl = g ^ (rB & 7);
        bfr[nt] = *(const bf16x8*)(Bs + ((size_t)rB * 8 + gl) * 8);
      }
#pragma unroll
      for (int mt = 0; mt < 4; ++mt)
#pragma unroll
        for (int nt = 0; nt < 4; ++nt)
          acc[mt][nt] = __builtin_amdgcn_mfma_f32_16x16x32_bf16(afr[mt], bfr[nt],
                                                                acc[mt][nt], 0, 0, 0);
    }
    __builtin_amdgcn_s_barrier();                   // all waves done reading buf[p&1]
    if (p < 2) ISSUE_PHASE(p + 2)                   // refill the buffer just freed
  }
#undef ISSUE_PHASE

  // epilogue: masked thresholded sum with symmetry weights
  float local = 0.f;
  int a_base = arow0 + wr * 64;
  int b_base = brow0 + wc * 64;              // 64-aligned
#pragma unroll
  for (int mt = 0; mt < 4; ++mt) {
#pragma unroll
    for (int r = 0; r < 4; ++r) {
      int a = a_base + mt * 16 + quad * 4 + r;
      uint64_t bits = *(const uint64_t*)(adj + (size_t)a * 256 + (b_base >> 5));
#pragma unroll
      for (int nt = 0; nt < 4; ++nt) {
        float v = acc[mt][nt][r];
        int boff = nt * 16 + l15;
        bool conn = (bits >> boff) & 1ull;
        float wgt;
        if (br != bc) wgt = 2.f;
        else {
          int b = b_base + boff;
          wgt = (a < b) ? 2.f : (a == b ? 1.f : 0.f);
        }
        if (!conn && v > THRESH) local += wgt * v;
      }
    }
  }
#pragma unroll
  for (int m = 1; m < 64; m <<= 1) local += __shfl_xor(local, m);
  float* red = (float*)LB;                   // LB free after final barrier
  if (lane == 0) red[wv] = local;
  __syncthreads();
  if (t == 0) pp[tb] = red[0] + red[1] + red[2] + red[3];   // NO atomic
}

// ---------- K11: homophily reduce + penalty-partials reduce + combine ----------
__global__ void k_final(const float* __restrict__ scores, const float* __restrict__ deg,
                        const float* __restrict__ pp, float* __restrict__ out) {
  __shared__ float redh[4];
  __shared__ float redp[4];
  int t = threadIdx.x;
  float acch = 0.f;
#pragma unroll 4
  for (int it = 0; it < 32; ++it) {
    int n = it * 256 + t;
    float dg = deg[n];
    acch += scores[n] / (dg == 0.f ? 1.f : dg);
  }
  float accp = 0.f;
#pragma unroll
  for (int it = 0; it < 9; ++it) {
    int idx = it * 256 + t;
    if (idx < 2080) accp += pp[idx];
  }
#pragma unroll
  for (int m = 1; m < 64; m <<= 1) {
    acch += __shfl_xor(acch, m);
    accp += __shfl_xor(accp, m);
  }
  if ((t & 63) == 0) { redh[t >> 6] = acch; redp[t >> 6] = accp; }
  __syncthreads();
  if (t == 0) {
    double h = -(double)(redh[0] + redh[1] + redh[2] + redh[3]) / 8192.0;
    double p = (double)(redp[0] + redp[1] + redp[2] + redp[3]) / (8192.0 * 8192.0);
    out[0] = (float)(h + p);
  }
}

extern "C" void kernel_launch(void* const* d_in, const int* in_sizes, int n_in,
                              void* d_out, int out_size, void* d_ws, size_t ws_size,
                              hipStream_t stream) {
  const float* z = (const float*)d_in[0];
  // d_in[1] = x_hat (unused by the reference)
  const int* ei = (const int*)d_in[2];
  const int* ej = ei + Ee;
  const int* k2u = (const int*)d_in[3];
  const int* u2k = (const int*)d_in[4];

  char* ws = (char*)d_ws;
  // zeroed region: [0, ZERO_BYTES)
  unsigned int* adj = (unsigned int*)(ws);               // 8 MiB
  float* colsum     = (float*)(ws + 8388608);            // 1 KiB
  float* scores     = (float*)(ws + 8389632);            // 32 KiB
  float* deg        = (float*)(ws + 8422400);            // 32 KiB
  const size_t ZERO_BYTES = 8455168;
  // non-zeroed scratch
  float* covp       = (float*)(ws + 8455296);            // 16 x 256 KiB = 4 MiB
  unsigned short* zT  = (unsigned short*)(ws + 12649600); // 4 MiB
  unsigned short* z2b = (unsigned short*)(ws + 16843904); // 4 MiB
  float* cor        = (float*)(ws + 21038208);           // 256 KiB
  float* norms      = (float*)(ws + 21300352);           // 32 KiB
  float* pp         = (float*)(ws + 21333120);           // 2080 floats (written by all blocks)

  hipMemsetAsync(d_ws, 0, ZERO_BYTES, stream);
  k_adj<<<1024, 256, 0, stream>>>(ei, ej, adj);
  k_transpose<<<dim3(128, 4), 256, 0, stream>>>(z, zT, colsum);
  k_covg<<<dim3(2, 2, 16), 256, 0, stream>>>(zT, covp);
  k_cor<<<256, 256, 0, stream>>>(covp, colsum, cor);
  k_z2<<<256, 256, 0, stream>>>(z, colsum, k2u, u2k, cor, z2b, norms);
  k_edge<<<2048, 256, 0, stream>>>(ei, ej, z2b, norms, scores, deg);
  k_penalty<<<2080, 256, 0, stream>>>(z2b, adj, pp);
  k_final<<<1, 256, 0, stream>>>(scores, deg, pp, (float*)d_out);
}

// Round 9
// 209.147 us; speedup vs baseline: 1.5918x; 1.0415x over previous
//
#include <hip/hip_runtime.h>
#include <stdint.h>
#include <math.h>

#define EPS_C 0.01f
#define THRESH 0.8f

constexpr int Nn = 8192;
constexpr int Ff = 256;
constexpr int Ee = 262144;

__device__ __forceinline__ float b2f(unsigned short u) {
  union { uint32_t i; float f; } v; v.i = ((uint32_t)u) << 16; return v.f;
}
__device__ __forceinline__ unsigned short f2b(float f) {
  union { uint32_t i; float f; } v; v.f = f;
  uint32_t r = v.i + 0x7FFFu + ((v.i >> 16) & 1u);
  return (unsigned short)(r >> 16);
}

typedef __bf16 bf16x8 __attribute__((ext_vector_type(8)));
typedef float f32x4 __attribute__((ext_vector_type(4)));

// ---------- K3a: transpose+quantize z -> zT bf16 [256][8192]; colsum fused ----------
__global__ void k_transpose(const float* __restrict__ z, unsigned short* __restrict__ zT,
                            float* __restrict__ colsum) {
  __shared__ float Ls[64][65];
  int n0 = blockIdx.x * 64;
  int c0 = blockIdx.y * 64;
  int t = threadIdx.x;
  int r = t >> 4;        // 0..15
  int cq = t & 15;       // 0..15
#pragma unroll
  for (int i = 0; i < 4; ++i) {
    int row = r + 16 * i;
    float4 v = *(const float4*)(z + (size_t)(n0 + row) * Ff + c0 + cq * 4);
    Ls[row][cq * 4 + 0] = v.x;
    Ls[row][cq * 4 + 1] = v.y;
    Ls[row][cq * 4 + 2] = v.z;
    Ls[row][cq * 4 + 3] = v.w;
  }
  __syncthreads();
  if (t < 64) {
    float s = 0.f;
#pragma unroll
    for (int rr = 0; rr < 64; ++rr) s += Ls[rr][t];
    atomicAdd(&colsum[c0 + t], s);
  }
  int cr = t >> 4;       // feature within tile
  int nq = t & 15;       // n-quad
#pragma unroll
  for (int i = 0; i < 4; ++i) {
    int c = cr + 16 * i;
    ushort4 o;
    o.x = f2b(Ls[nq * 4 + 0][c]);
    o.y = f2b(Ls[nq * 4 + 1][c]);
    o.z = f2b(Ls[nq * 4 + 2][c]);
    o.w = f2b(Ls[nq * 4 + 3][c]);
    *(ushort4*)(zT + (size_t)(c0 + c) * Nn + n0 + nq * 4) = o;
  }
}

// ---------- K3b: G = zT @ zT^T via MFMA, split-K=16 partials (LDS-staged) ----------
__global__ __launch_bounds__(256, 2) void k_covg(const unsigned short* __restrict__ zT,
                                                 float* __restrict__ covp) {
  int bx = blockIdx.x, by = blockIdx.y, p = blockIdx.z;
  __shared__ __align__(16) unsigned short As[128 * 64];
  __shared__ __align__(16) unsigned short Bs[128 * 64];
  int t = threadIdx.x;
  int lane = t & 63, wv = t >> 6;
  int wr = wv >> 1, wc = wv & 1;
  int quad = lane >> 4, l15 = lane & 15;
  int a0 = by * 128, b0 = bx * 128;

  f32x4 acc[4][4];
#pragma unroll
  for (int i = 0; i < 4; ++i)
#pragma unroll
    for (int j = 0; j < 4; ++j) acc[i][j] = (f32x4){0.f, 0.f, 0.f, 0.f};

  for (int kk = 0; kk < 8; ++kk) {
    int k0 = p * 512 + kk * 64;
#pragma unroll
    for (int it = 0; it < 4; ++it) {
      int s = it * 256 + t;
      int r = s >> 3;
      int g = (s & 7) ^ (r & 7);
      const unsigned short* ga = zT + (size_t)(a0 + r) * Nn + k0 + g * 8;
      const unsigned short* gb = zT + (size_t)(b0 + r) * Nn + k0 + g * 8;
      __builtin_amdgcn_global_load_lds((const __attribute__((address_space(1))) void*)ga,
                                       (__attribute__((address_space(3))) void*)(As + s * 8),
                                       16, 0, 0);
      __builtin_amdgcn_global_load_lds((const __attribute__((address_space(1))) void*)gb,
                                       (__attribute__((address_space(3))) void*)(Bs + s * 8),
                                       16, 0, 0);
    }
    __syncthreads();
#pragma unroll
    for (int kc = 0; kc < 2; ++kc) {
      bf16x8 afr[4], bfr[4];
#pragma unroll
      for (int mt = 0; mt < 4; ++mt) {
        int rA = wr * 64 + mt * 16 + l15;
        int g = kc * 4 + quad;
        int gl = g ^ (rA & 7);
        afr[mt] = *(const bf16x8*)(As + ((size_t)rA * 8 + gl) * 8);
      }
#pragma unroll
      for (int nt = 0; nt < 4; ++nt) {
        int rB = wc * 64 + nt * 16 + l15;
        int g = kc * 4 + quad;
        int gl = g ^ (rB & 7);
        bfr[nt] = *(const bf16x8*)(Bs + ((size_t)rB * 8 + gl) * 8);
      }
#pragma unroll
      for (int mt = 0; mt < 4; ++mt)
#pragma unroll
        for (int nt = 0; nt < 4; ++nt)
          acc[mt][nt] = __builtin_amdgcn_mfma_f32_16x16x32_bf16(afr[mt], bfr[nt],
                                                                acc[mt][nt], 0, 0, 0);
    }
    __syncthreads();
  }

  float* outp = covp + (size_t)p * 65536;
#pragma unroll
  for (int mt = 0; mt < 4; ++mt)
#pragma unroll
    for (int r = 0; r < 4; ++r) {
      int a = a0 + wr * 64 + mt * 16 + quad * 4 + r;
#pragma unroll
      for (int nt = 0; nt < 4; ++nt) {
        int b = b0 + wc * 64 + nt * 16 + l15;
        outp[(size_t)a * Ff + b] = acc[mt][nt][r];
      }
    }
}

// ---------- K4: cor from partials (diag/std fused) ----------
__global__ void k_cor(const float* __restrict__ covp, const float* __restrict__ colsum,
                      float* __restrict__ cor) {
  __shared__ float sd[256];
  int a = blockIdx.x, b = threadIdx.x;
  float mb = colsum[b] * (1.f / 8192.f);
  float gb = 0.f;
#pragma unroll
  for (int p = 0; p < 16; ++p) gb += covp[(size_t)p * 65536 + b * 257];
  float sb = sqrtf(gb - 8192.f * mb * mb);
  sd[b] = sb;
  float g = 0.f;
#pragma unroll
  for (int p = 0; p < 16; ++p) g += covp[(size_t)p * 65536 + a * Ff + b];
  __syncthreads();
  float c = 0.f;
  if (a != b) {
    float ma = colsum[a] * (1.f / 8192.f);
    float cv = g - 8192.f * ma * mb;
    c = cv / (sd[a] * sb);
    if (c != c) c = 0.f;                 // nan_to_num
    c = fminf(1.f, fmaxf(-1.f, c));      // clip
  }
  cor[a * Ff + b] = c;
}

// ---------- K5: z2 = z + EPS*(w*zm)@cor; bf16 + fp8 outputs; w + norms fused ----------
// 512 blocks x 16 rows: 2 waves/SIMD (R8's 256x32 ran at 1 wave/SIMD, latency-exposed)
__global__ __launch_bounds__(256) void k_z2(const float* __restrict__ z,
    const float* __restrict__ colsum, const int* __restrict__ k2u,
    const int* __restrict__ u2k, const float* __restrict__ cor,
    unsigned short* __restrict__ z2b, unsigned char* __restrict__ z2f8,
    float* __restrict__ norms) {
  __shared__ float Wl[16 * 256];
  __shared__ float ws_[16];
  int t = threadIdx.x;
  int row0 = blockIdx.x * 16;
  if (t < 16) {
    int row = row0 + t;
    ws_[t] = powf(0.9f, (float)k2u[row]) + 1.f - powf(0.9f, (float)u2k[row]);
  }
  __syncthreads();
  float mt = colsum[t] * (1.f / 8192.f);
#pragma unroll
  for (int rr = 0; rr < 16; ++rr) {
    int row = row0 + rr;
    Wl[rr * 256 + t] = ws_[rr] * (z[(size_t)row * Ff + t] - mt);
  }
  __syncthreads();
  int tc = t & 63, tr = t >> 6;   // wave tr owns rows [tr*4, tr*4+4); lane == tc
  float acc[4][4];
#pragma unroll
  for (int i = 0; i < 4; ++i)
#pragma unroll
    for (int j = 0; j < 4; ++j) acc[i][j] = 0.f;
  const float* corc = cor + tc * 4;
  for (int k = 0; k < 256; ++k) {
    float4 c4 = *(const float4*)(corc + (size_t)k * 256);
#pragma unroll
    for (int rr = 0; rr < 4; ++rr) {
      float wv = Wl[(tr * 4 + rr) * 256 + k];
      acc[rr][0] = fmaf(wv, c4.x, acc[rr][0]);
      acc[rr][1] = fmaf(wv, c4.y, acc[rr][1]);
      acc[rr][2] = fmaf(wv, c4.z, acc[rr][2]);
      acc[rr][3] = fmaf(wv, c4.w, acc[rr][3]);
    }
  }
#pragma unroll
  for (int rr = 0; rr < 4; ++rr) {
    int row = row0 + tr * 4 + rr;
    float4 zv = *(const float4*)(z + (size_t)row * Ff + tc * 4);
    float x0 = zv.x + EPS_C * acc[rr][0];
    float x1 = zv.y + EPS_C * acc[rr][1];
    float x2 = zv.z + EPS_C * acc[rr][2];
    float x3 = zv.w + EPS_C * acc[rr][3];
    ushort4 o;
    o.x = f2b(x0); o.y = f2b(x1); o.z = f2b(x2); o.w = f2b(x3);
    *(ushort4*)(z2b + (size_t)row * Ff + tc * 4) = o;
    int pk = __builtin_amdgcn_cvt_pk_fp8_f32(x0, x1, 0, 0);
    pk = __builtin_amdgcn_cvt_pk_fp8_f32(x2, x3, pk, 1);
    *(unsigned int*)(z2f8 + (size_t)row * Ff + tc * 4) = (unsigned int)pk;
    float s = x0 * x0 + x1 * x1 + x2 * x2 + x3 * x3;
#pragma unroll
    for (int m = 1; m < 64; m <<= 1) s += __shfl_xor(s, m);
    if (tc == 0) norms[row] = fmaxf(sqrtf(s), 1e-8f);
  }
}

// ---------- K7: adjacency bitmask ----------
__global__ void k_adj(const int* __restrict__ ei, const int* __restrict__ ej,
                      unsigned int* __restrict__ adj) {
  int e = blockIdx.x * 256 + threadIdx.x;
  unsigned int i = (unsigned int)ei[e], j = (unsigned int)ej[e];
  size_t b1 = (size_t)i * Nn + j;
  size_t b2 = (size_t)j * Nn + i;
  atomicOr(&adj[b1 >> 5], 1u << (b1 & 31));
  atomicOr(&adj[b2 >> 5], 1u << (b2 & 31));
}

// ---------- K8: per-edge cosine, batched (bf16) ----------
__global__ __launch_bounds__(256) void k_edge(const int* __restrict__ ei,
                       const int* __restrict__ ej,
                       const unsigned short* __restrict__ z2b,
                       const float* __restrict__ norms,
                       float* __restrict__ scores, float* __restrict__ deg) {
  int t = threadIdx.x;
  int wv = t >> 6, lane = t & 63;
  int half = lane >> 5;
  int l32 = lane & 31;
  int gw = blockIdx.x * 4 + wv;
  int ebase = gw * 32;
#pragma unroll 2
  for (int it = 0; it < 16; ++it) {
    int e = ebase + it * 2 + half;
    int i = ei[e], j = ej[e];
    uint4 ua = *(const uint4*)(z2b + (size_t)i * Ff + l32 * 8);
    uint4 ub = *(const uint4*)(z2b + (size_t)j * Ff + l32 * 8);
    float d = 0.f;
    const uint32_t* pa = (const uint32_t*)&ua;
    const uint32_t* pb = (const uint32_t*)&ub;
#pragma unroll
    for (int q = 0; q < 4; ++q) {
      union { uint32_t u; float f; } alo, ahi, blo, bhi;
      alo.u = pa[q] << 16;  ahi.u = pa[q] & 0xffff0000u;
      blo.u = pb[q] << 16;  bhi.u = pb[q] & 0xffff0000u;
      d = fmaf(alo.f, blo.f, d);
      d = fmaf(ahi.f, bhi.f, d);
    }
#pragma unroll
    for (int m = 1; m < 32; m <<= 1) d += __shfl_xor(d, m);
    if (l32 == 0) {
      float sim = d / (norms[i] * norms[j]);
      atomicAdd(&scores[i], sim);
      atomicAdd(&deg[i], 1.f);
    }
  }
}

// ---------- K10: fused penalty GEMM — fp8, 32KB ping-pong, 4 blocks/CU ----------
__global__ __launch_bounds__(256, 4) void k_penalty(const unsigned char* __restrict__ z2f8,
    const unsigned int* __restrict__ adj, float* __restrict__ pp) {
  // triangular decode: 2080 blocks -> (br, bc), br <= bc
  int tb = blockIdx.x;
  int br = (int)(64.5 - sqrt(64.5 * 64.5 - 2.0 * (double)tb));
  while ((br + 1) * 64 - ((br + 1) * br) / 2 <= tb) ++br;
  while (br * 64 - (br * (br - 1)) / 2 > tb) --br;
  int bc = br + (tb - (br * 64 - (br * (br - 1)) / 2));

  __shared__ __align__(16) unsigned char LB[32768];  // 2 phases x (A 8KB + B 8KB)
  int t = threadIdx.x;
  int lane = t & 63;
  int wv = t >> 6;
  int wr = wv >> 1, wc = wv & 1;             // 2x2 waves, each 64x64
  int quad = lane >> 4;
  int l15 = lane & 15;
  int arow0 = br * 128, brow0 = bc * 128;

  f32x4 acc[4][4];
#pragma unroll
  for (int i = 0; i < 4; ++i)
#pragma unroll
    for (int j = 0; j < 4; ++j) acc[i][j] = (f32x4){0.f, 0.f, 0.f, 0.f};

  // stage phase p (64-wide K panel, fp8): A/B 128x64B; 4x16B loads/thread
  // swizzle granules with (r&3)^((r>>2)&3) so frag ds_read_b64 is 2-way (free)
#define ISSUE_PHASE(p)                                                                   \
  {                                                                                      \
    unsigned char* buf = LB + ((p) & 1) * 16384;                                         \
    int k0 = (p) * 64;                                                                   \
    _Pragma("unroll")                                                                    \
    for (int it = 0; it < 2; ++it) {                                                     \
      int s = it * 256 + t;                                                              \
      int r = s >> 2;                                                                    \
      int gs = (s & 3) ^ (r & 3) ^ ((r >> 2) & 3);                                       \
      const unsigned char* ga = z2f8 + (size_t)(arow0 + r) * Ff + k0 + gs * 16;          \
      const unsigned char* gb = z2f8 + (size_t)(brow0 + r) * Ff + k0 + gs * 16;          \
      __builtin_amdgcn_global_load_lds((const __attribute__((address_space(1))) void*)ga,\
                                       (__attribute__((address_space(3))) void*)(buf + s * 16),      \
                                       16, 0, 0);                                        \
      __builtin_amdgcn_global_load_lds((const __attribute__((address_space(1))) void*)gb,\
                                       (__attribute__((address_space(3))) void*)(buf + 8192 + s * 16),\
                                       16, 0, 0);                                        \
    }                                                                                    \
  }

  ISSUE_PHASE(0)
  ISSUE_PHASE(1)
#pragma unroll
  for (int p = 0; p < 4; ++p) {
    if (p < 3) __builtin_amdgcn_s_waitcnt(0xF74);   // vmcnt(4): this phase done, next in flight
    else       __builtin_amdgcn_s_waitcnt(0xF70);   // vmcnt(0)
    __builtin_amdgcn_s_barrier();
    const unsigned char* As = LB + (p & 1) * 16384;
    const unsigned char* Bs = As + 8192;
#pragma unroll
    for (int kc = 0; kc < 2; ++kc) {
      long a8[4], b8[4];
      int gidx = kc * 2 + (quad >> 1);
      int bo = (quad & 1) * 8;
#pragma unroll
      for (int mt = 0; mt < 4; ++mt) {
        int rA = wr * 64 + mt * 16 + l15;
        int gl = gidx ^ (rA & 3) ^ ((rA >> 2) & 3);
        a8[mt] = *(const long*)(As + rA * 64 + gl * 16 + bo);
      }
#pragma unroll
      for (int nt = 0; nt < 4; ++nt) {
        int rB = wc * 64 + nt * 16 + l15;
        int gl = gidx ^ (rB & 3) ^ ((rB >> 2) & 3);
        b8[nt] = *(const long*)(Bs + rB * 64 + gl * 16 + bo);
      }
#pragma unroll
      for (int mt = 0; mt < 4; ++mt)
#pragma unroll
        for (int nt = 0; nt < 4; ++nt)
          acc[mt][nt] = __builtin_amdgcn_mfma_f32_16x16x32_fp8_fp8(a8[mt], b8[nt],
                                                                   acc[mt][nt], 0, 0, 0);
    }
    __builtin_amdgcn_s_barrier();                   // all waves done reading buf[p&1]
    if (p < 2) ISSUE_PHASE(p + 2)                   // refill the buffer just freed
  }
#undef ISSUE_PHASE

  // epilogue: masked thresholded sum with symmetry weights
  float local = 0.f;
  int a_base = arow0 + wr * 64;
  int b_base = brow0 + wc * 64;              // 64-aligned
#pragma unroll
  for (int mt = 0; mt < 4; ++mt) {
#pragma unroll
    for (int r = 0; r < 4; ++r) {
      int a = a_base + mt * 16 + quad * 4 + r;
      uint64_t bits = *(const uint64_t*)(adj + (size_t)a * 256 + (b_base >> 5));
#pragma unroll
      for (int nt = 0; nt < 4; ++nt) {
        float v = acc[mt][nt][r];
        int boff = nt * 16 + l15;
        bool conn = (bits >> boff) & 1ull;
        float wgt;
        if (br != bc) wgt = 2.f;
        else {
          int b = b_base + boff;
          wgt = (a < b) ? 2.f : (a == b ? 1.f : 0.f);
        }
        if (!conn && v > THRESH) local += wgt * v;
      }
    }
  }
#pragma unroll
  for (int m = 1; m < 64; m <<= 1) local += __shfl_xor(local, m);
  float* red = (float*)LB;                   // LB free after final barrier
  if (lane == 0) red[wv] = local;
  __syncthreads();
  if (t == 0) pp[tb] = red[0] + red[1] + red[2] + red[3];   // NO atomic
}

// ---------- K11: homophily reduce + penalty-partials reduce + combine ----------
__global__ void k_final(const float* __restrict__ scores, const float* __restrict__ deg,
                        const float* __restrict__ pp, float* __restrict__ out) {
  __shared__ float redh[4];
  __shared__ float redp[4];
  int t = threadIdx.x;
  float acch = 0.f;
#pragma unroll 4
  for (int it = 0; it < 32; ++it) {
    int n = it * 256 + t;
    float dg = deg[n];
    acch += scores[n] / (dg == 0.f ? 1.f : dg);
  }
  float accp = 0.f;
#pragma unroll
  for (int it = 0; it < 9; ++it) {
    int idx = it * 256 + t;
    if (idx < 2080) accp += pp[idx];
  }
#pragma unroll
  for (int m = 1; m < 64; m <<= 1) {
    acch += __shfl_xor(acch, m);
    accp += __shfl_xor(accp, m);
  }
  if ((t & 63) == 0) { redh[t >> 6] = acch; redp[t >> 6] = accp; }
  __syncthreads();
  if (t == 0) {
    double h = -(double)(redh[0] + redh[1] + redh[2] + redh[3]) / 8192.0;
    double p = (double)(redp[0] + redp[1] + redp[2] + redp[3]) / (8192.0 * 8192.0);
    out[0] = (float)(h + p);
  }
}

extern "C" void kernel_launch(void* const* d_in, const int* in_sizes, int n_in,
                              void* d_out, int out_size, void* d_ws, size_t ws_size,
                              hipStream_t stream) {
  const float* z = (const float*)d_in[0];
  // d_in[1] = x_hat (unused by the reference)
  const int* ei = (const int*)d_in[2];
  const int* ej = ei + Ee;
  const int* k2u = (const int*)d_in[3];
  const int* u2k = (const int*)d_in[4];

  char* ws = (char*)d_ws;
  // zeroed region: [0, ZERO_BYTES)
  unsigned int* adj = (unsigned int*)(ws);               // 8 MiB
  float* colsum     = (float*)(ws + 8388608);            // 1 KiB
  float* scores     = (float*)(ws + 8389632);            // 32 KiB
  float* deg        = (float*)(ws + 8422400);            // 32 KiB
  const size_t ZERO_BYTES = 8455168;
  // non-zeroed scratch
  float* covp       = (float*)(ws + 8455296);            // 16 x 256 KiB = 4 MiB
  unsigned short* zT  = (unsigned short*)(ws + 12649600); // 4 MiB
  unsigned short* z2b = (unsigned short*)(ws + 16843904); // 4 MiB
  float* cor        = (float*)(ws + 21038208);           // 256 KiB
  float* norms      = (float*)(ws + 21300352);           // 32 KiB
  float* pp         = (float*)(ws + 21333120);           // 2080 floats
  unsigned char* z2f8 = (unsigned char*)(ws + 21341568); // 2 MiB fp8 e4m3

  hipMemsetAsync(d_ws, 0, ZERO_BYTES, stream);
  k_adj<<<1024, 256, 0, stream>>>(ei, ej, adj);
  k_transpose<<<dim3(128, 4), 256, 0, stream>>>(z, zT, colsum);
  k_covg<<<dim3(2, 2, 16), 256, 0, stream>>>(zT, covp);
  k_cor<<<256, 256, 0, stream>>>(covp, colsum, cor);
  k_z2<<<512, 256, 0, stream>>>(z, colsum, k2u, u2k, cor, z2b, z2f8, norms);
  k_edge<<<2048, 256, 0, stream>>>(ei, ej, z2b, norms, scores, deg);
  k_penalty<<<2080, 256, 0, stream>>>(z2f8, adj, pp);
  k_final<<<1, 256, 0, stream>>>(scores, deg, pp, (float*)d_out);
}

// Round 10
// 205.061 us; speedup vs baseline: 1.6235x; 1.0199x over previous
//
#include <hip/hip_runtime.h>
#include <stdint.h>
#include <math.h>

#define EPS_C 0.01f
#define THRESH 0.8f

constexpr int Nn = 8192;
constexpr int Ff = 256;
constexpr int Ee = 262144;

__device__ __forceinline__ float b2f(unsigned short u) {
  union { uint32_t i; float f; } v; v.i = ((uint32_t)u) << 16; return v.f;
}
__device__ __forceinline__ unsigned short f2b(float f) {
  union { uint32_t i; float f; } v; v.f = f;
  uint32_t r = v.i + 0x7FFFu + ((v.i >> 16) & 1u);
  return (unsigned short)(r >> 16);
}

typedef __bf16 bf16x8 __attribute__((ext_vector_type(8)));
typedef float f32x4 __attribute__((ext_vector_type(4)));
typedef int i32x4 __attribute__((ext_vector_type(4)));
typedef int i32x8 __attribute__((ext_vector_type(8)));

// ---------- K3a: transpose+quantize z -> zT bf16 [256][8192]; colsum fused ----------
__global__ void k_transpose(const float* __restrict__ z, unsigned short* __restrict__ zT,
                            float* __restrict__ colsum) {
  __shared__ float Ls[64][65];
  int n0 = blockIdx.x * 64;
  int c0 = blockIdx.y * 64;
  int t = threadIdx.x;
  int r = t >> 4;        // 0..15
  int cq = t & 15;       // 0..15
#pragma unroll
  for (int i = 0; i < 4; ++i) {
    int row = r + 16 * i;
    float4 v = *(const float4*)(z + (size_t)(n0 + row) * Ff + c0 + cq * 4);
    Ls[row][cq * 4 + 0] = v.x;
    Ls[row][cq * 4 + 1] = v.y;
    Ls[row][cq * 4 + 2] = v.z;
    Ls[row][cq * 4 + 3] = v.w;
  }
  __syncthreads();
  if (t < 64) {
    float s = 0.f;
#pragma unroll
    for (int rr = 0; rr < 64; ++rr) s += Ls[rr][t];
    atomicAdd(&colsum[c0 + t], s);
  }
  int cr = t >> 4;       // feature within tile
  int nq = t & 15;       // n-quad
#pragma unroll
  for (int i = 0; i < 4; ++i) {
    int c = cr + 16 * i;
    ushort4 o;
    o.x = f2b(Ls[nq * 4 + 0][c]);
    o.y = f2b(Ls[nq * 4 + 1][c]);
    o.z = f2b(Ls[nq * 4 + 2][c]);
    o.w = f2b(Ls[nq * 4 + 3][c]);
    *(ushort4*)(zT + (size_t)(c0 + c) * Nn + n0 + nq * 4) = o;
  }
}

// ---------- K3b: G = zT @ zT^T via MFMA, split-K=16 partials (LDS-staged) ----------
__global__ __launch_bounds__(256, 2) void k_covg(const unsigned short* __restrict__ zT,
                                                 float* __restrict__ covp) {
  int bx = blockIdx.x, by = blockIdx.y, p = blockIdx.z;
  __shared__ __align__(16) unsigned short As[128 * 64];
  __shared__ __align__(16) unsigned short Bs[128 * 64];
  int t = threadIdx.x;
  int lane = t & 63, wv = t >> 6;
  int wr = wv >> 1, wc = wv & 1;
  int quad = lane >> 4, l15 = lane & 15;
  int a0 = by * 128, b0 = bx * 128;

  f32x4 acc[4][4];
#pragma unroll
  for (int i = 0; i < 4; ++i)
#pragma unroll
    for (int j = 0; j < 4; ++j) acc[i][j] = (f32x4){0.f, 0.f, 0.f, 0.f};

  for (int kk = 0; kk < 8; ++kk) {
    int k0 = p * 512 + kk * 64;
#pragma unroll
    for (int it = 0; it < 4; ++it) {
      int s = it * 256 + t;
      int r = s >> 3;
      int g = (s & 7) ^ (r & 7);
      const unsigned short* ga = zT + (size_t)(a0 + r) * Nn + k0 + g * 8;
      const unsigned short* gb = zT + (size_t)(b0 + r) * Nn + k0 + g * 8;
      __builtin_amdgcn_global_load_lds((const __attribute__((address_space(1))) void*)ga,
                                       (__attribute__((address_space(3))) void*)(As + s * 8),
                                       16, 0, 0);
      __builtin_amdgcn_global_load_lds((const __attribute__((address_space(1))) void*)gb,
                                       (__attribute__((address_space(3))) void*)(Bs + s * 8),
                                       16, 0, 0);
    }
    __syncthreads();
#pragma unroll
    for (int kc = 0; kc < 2; ++kc) {
      bf16x8 afr[4], bfr[4];
#pragma unroll
      for (int mt = 0; mt < 4; ++mt) {
        int rA = wr * 64 + mt * 16 + l15;
        int g = kc * 4 + quad;
        int gl = g ^ (rA & 7);
        afr[mt] = *(const bf16x8*)(As + ((size_t)rA * 8 + gl) * 8);
      }
#pragma unroll
      for (int nt = 0; nt < 4; ++nt) {
        int rB = wc * 64 + nt * 16 + l15;
        int g = kc * 4 + quad;
        int gl = g ^ (rB & 7);
        bfr[nt] = *(const bf16x8*)(Bs + ((size_t)rB * 8 + gl) * 8);
      }
#pragma unroll
      for (int mt = 0; mt < 4; ++mt)
#pragma unroll
        for (int nt = 0; nt < 4; ++nt)
          acc[mt][nt] = __builtin_amdgcn_mfma_f32_16x16x32_bf16(afr[mt], bfr[nt],
                                                                acc[mt][nt], 0, 0, 0);
    }
    __syncthreads();
  }

  float* outp = covp + (size_t)p * 65536;
#pragma unroll
  for (int mt = 0; mt < 4; ++mt)
#pragma unroll
    for (int r = 0; r < 4; ++r) {
      int a = a0 + wr * 64 + mt * 16 + quad * 4 + r;
#pragma unroll
      for (int nt = 0; nt < 4; ++nt) {
        int b = b0 + wc * 64 + nt * 16 + l15;
        outp[(size_t)a * Ff + b] = acc[mt][nt][r];
      }
    }
}

// ---------- K4: cor from partials (diag/std fused) ----------
__global__ void k_cor(const float* __restrict__ covp, const float* __restrict__ colsum,
                      float* __restrict__ cor) {
  __shared__ float sd[256];
  int a = blockIdx.x, b = threadIdx.x;
  float mb = colsum[b] * (1.f / 8192.f);
  float gb = 0.f;
#pragma unroll
  for (int p = 0; p < 16; ++p) gb += covp[(size_t)p * 65536 + b * 257];
  float sb = sqrtf(gb - 8192.f * mb * mb);
  sd[b] = sb;
  float g = 0.f;
#pragma unroll
  for (int p = 0; p < 16; ++p) g += covp[(size_t)p * 65536 + a * Ff + b];
  __syncthreads();
  float c = 0.f;
  if (a != b) {
    float ma = colsum[a] * (1.f / 8192.f);
    float cv = g - 8192.f * ma * mb;
    c = cv / (sd[a] * sb);
    if (c != c) c = 0.f;                 // nan_to_num
    c = fminf(1.f, fmaxf(-1.f, c));      // clip
  }
  cor[a * Ff + b] = c;
}

// ---------- K5: z2 = z + EPS*(w*zm)@cor; bf16 + fp8 outputs; w + norms fused ----------
__global__ __launch_bounds__(256) void k_z2(const float* __restrict__ z,
    const float* __restrict__ colsum, const int* __restrict__ k2u,
    const int* __restrict__ u2k, const float* __restrict__ cor,
    unsigned short* __restrict__ z2b, unsigned char* __restrict__ z2f8,
    float* __restrict__ norms) {
  __shared__ float Wl[16 * 256];
  __shared__ float ws_[16];
  int t = threadIdx.x;
  int row0 = blockIdx.x * 16;
  if (t < 16) {
    int row = row0 + t;
    ws_[t] = powf(0.9f, (float)k2u[row]) + 1.f - powf(0.9f, (float)u2k[row]);
  }
  __syncthreads();
  float mt = colsum[t] * (1.f / 8192.f);
#pragma unroll
  for (int rr = 0; rr < 16; ++rr) {
    int row = row0 + rr;
    Wl[rr * 256 + t] = ws_[rr] * (z[(size_t)row * Ff + t] - mt);
  }
  __syncthreads();
  int tc = t & 63, tr = t >> 6;   // wave tr owns rows [tr*4, tr*4+4); lane == tc
  float acc[4][4];
#pragma unroll
  for (int i = 0; i < 4; ++i)
#pragma unroll
    for (int j = 0; j < 4; ++j) acc[i][j] = 0.f;
  const float* corc = cor + tc * 4;
  for (int k = 0; k < 256; ++k) {
    float4 c4 = *(const float4*)(corc + (size_t)k * 256);
#pragma unroll
    for (int rr = 0; rr < 4; ++rr) {
      float wv = Wl[(tr * 4 + rr) * 256 + k];
      acc[rr][0] = fmaf(wv, c4.x, acc[rr][0]);
      acc[rr][1] = fmaf(wv, c4.y, acc[rr][1]);
      acc[rr][2] = fmaf(wv, c4.z, acc[rr][2]);
      acc[rr][3] = fmaf(wv, c4.w, acc[rr][3]);
    }
  }
#pragma unroll
  for (int rr = 0; rr < 4; ++rr) {
    int row = row0 + tr * 4 + rr;
    float4 zv = *(const float4*)(z + (size_t)row * Ff + tc * 4);
    float x0 = zv.x + EPS_C * acc[rr][0];
    float x1 = zv.y + EPS_C * acc[rr][1];
    float x2 = zv.z + EPS_C * acc[rr][2];
    float x3 = zv.w + EPS_C * acc[rr][3];
    ushort4 o;
    o.x = f2b(x0); o.y = f2b(x1); o.z = f2b(x2); o.w = f2b(x3);
    *(ushort4*)(z2b + (size_t)row * Ff + tc * 4) = o;
    int pk = __builtin_amdgcn_cvt_pk_fp8_f32(x0, x1, 0, 0);
    pk = __builtin_amdgcn_cvt_pk_fp8_f32(x2, x3, pk, 1);
    *(unsigned int*)(z2f8 + (size_t)row * Ff + tc * 4) = (unsigned int)pk;
    float s = x0 * x0 + x1 * x1 + x2 * x2 + x3 * x3;
#pragma unroll
    for (int m = 1; m < 64; m <<= 1) s += __shfl_xor(s, m);
    if (tc == 0) norms[row] = fmaxf(sqrtf(s), 1e-8f);
  }
}

// ---------- K7: adjacency bitmask ----------
__global__ void k_adj(const int* __restrict__ ei, const int* __restrict__ ej,
                      unsigned int* __restrict__ adj) {
  int e = blockIdx.x * 256 + threadIdx.x;
  unsigned int i = (unsigned int)ei[e], j = (unsigned int)ej[e];
  size_t b1 = (size_t)i * Nn + j;
  size_t b2 = (size_t)j * Nn + i;
  atomicOr(&adj[b1 >> 5], 1u << (b1 & 31));
  atomicOr(&adj[b2 >> 5], 1u << (b2 & 31));
}

// ---------- K8: per-edge cosine, batched (bf16) ----------
__global__ __launch_bounds__(256) void k_edge(const int* __restrict__ ei,
                       const int* __restrict__ ej,
                       const unsigned short* __restrict__ z2b,
                       const float* __restrict__ norms,
                       float* __restrict__ scores, float* __restrict__ deg) {
  int t = threadIdx.x;
  int wv = t >> 6, lane = t & 63;
  int half = lane >> 5;
  int l32 = lane & 31;
  int gw = blockIdx.x * 4 + wv;
  int ebase = gw * 32;
#pragma unroll 2
  for (int it = 0; it < 16; ++it) {
    int e = ebase + it * 2 + half;
    int i = ei[e], j = ej[e];
    uint4 ua = *(const uint4*)(z2b + (size_t)i * Ff + l32 * 8);
    uint4 ub = *(const uint4*)(z2b + (size_t)j * Ff + l32 * 8);
    float d = 0.f;
    const uint32_t* pa = (const uint32_t*)&ua;
    const uint32_t* pb = (const uint32_t*)&ub;
#pragma unroll
    for (int q = 0; q < 4; ++q) {
      union { uint32_t u; float f; } alo, ahi, blo, bhi;
      alo.u = pa[q] << 16;  ahi.u = pa[q] & 0xffff0000u;
      blo.u = pb[q] << 16;  bhi.u = pb[q] & 0xffff0000u;
      d = fmaf(alo.f, blo.f, d);
      d = fmaf(ahi.f, bhi.f, d);
    }
#pragma unroll
    for (int m = 1; m < 32; m <<= 1) d += __shfl_xor(d, m);
    if (l32 == 0) {
      float sim = d / (norms[i] * norms[j]);
      atomicAdd(&scores[i], sim);
      atomicAdd(&deg[i], 1.f);
    }
  }
}

// ---------- K10: fused penalty GEMM — MX-scaled fp8 K=128 (2x rate), 2 phases ----------
__global__ __launch_bounds__(256, 2) void k_penalty(const unsigned char* __restrict__ z2f8,
    const unsigned int* __restrict__ adj, float* __restrict__ pp) {
  // triangular decode: 2080 blocks -> (br, bc), br <= bc
  int tb = blockIdx.x;
  int br = (int)(64.5 - sqrt(64.5 * 64.5 - 2.0 * (double)tb));
  while ((br + 1) * 64 - ((br + 1) * br) / 2 <= tb) ++br;
  while (br * 64 - (br * (br - 1)) / 2 > tb) --br;
  int bc = br + (tb - (br * 64 - (br * (br - 1)) / 2));

  __shared__ __align__(16) unsigned char LB[65536];  // 2 phases x (A 16KB + B 16KB)
  int t = threadIdx.x;
  int lane = t & 63;
  int wv = t >> 6;
  int wr = wv >> 1, wc = wv & 1;             // 2x2 waves, each 64x64
  int quad = lane >> 4;
  int l15 = lane & 15;
  int arow0 = br * 128, brow0 = bc * 128;

  f32x4 acc[4][4];
#pragma unroll
  for (int i = 0; i < 4; ++i)
#pragma unroll
    for (int j = 0; j < 4; ++j) acc[i][j] = (f32x4){0.f, 0.f, 0.f, 0.f};

  // phase p = K-panel of 128 fp8 bytes: A,B 128 rows x 128B, 16B granules
  // granule g of row r stored at slot g^(r&7) -> fragment reads are 2-way aliased (free)
#define ISSUE_PHASE(p)                                                                   \
  {                                                                                      \
    unsigned char* buf = LB + (p) * 32768;                                               \
    int k0 = (p) * 128;                                                                  \
    _Pragma("unroll")                                                                    \
    for (int it = 0; it < 4; ++it) {                                                     \
      int s = it * 256 + t;                                                              \
      int r = s >> 3;                                                                    \
      int g = (s & 7) ^ (r & 7);                                                         \
      const unsigned char* ga = z2f8 + (size_t)(arow0 + r) * Ff + k0 + g * 16;           \
      const unsigned char* gb = z2f8 + (size_t)(brow0 + r) * Ff + k0 + g * 16;           \
      __builtin_amdgcn_global_load_lds((const __attribute__((address_space(1))) void*)ga,\
                                       (__attribute__((address_space(3))) void*)(buf + s * 16),      \
                                       16, 0, 0);                                        \
      __builtin_amdgcn_global_load_lds((const __attribute__((address_space(1))) void*)gb,\
                                       (__attribute__((address_space(3))) void*)(buf + 16384 + s * 16),\
                                       16, 0, 0);                                        \
    }                                                                                    \
  }

  ISSUE_PHASE(0)
  ISSUE_PHASE(1)
#pragma unroll
  for (int p = 0; p < 2; ++p) {
    if (p == 0) __builtin_amdgcn_s_waitcnt(0xF78);   // vmcnt(8): phase0 done, phase1 in flight
    else        __builtin_amdgcn_s_waitcnt(0xF70);   // vmcnt(0)
    __builtin_amdgcn_s_barrier();
    const unsigned char* As = LB + p * 32768;
    const unsigned char* Bs = As + 16384;
    i32x8 a8[4], b8[4];
#pragma unroll
    for (int mt = 0; mt < 4; ++mt) {
      int rA = wr * 64 + mt * 16 + l15;
      int g0 = (2 * quad) ^ (rA & 7), g1 = (2 * quad + 1) ^ (rA & 7);
      i32x4 lo = *(const i32x4*)(As + rA * 128 + g0 * 16);
      i32x4 hi = *(const i32x4*)(As + rA * 128 + g1 * 16);
      a8[mt] = (i32x8){lo[0], lo[1], lo[2], lo[3], hi[0], hi[1], hi[2], hi[3]};
    }
#pragma unroll
    for (int nt = 0; nt < 4; ++nt) {
      int rB = wc * 64 + nt * 16 + l15;
      int g0 = (2 * quad) ^ (rB & 7), g1 = (2 * quad + 1) ^ (rB & 7);
      i32x4 lo = *(const i32x4*)(Bs + rB * 128 + g0 * 16);
      i32x4 hi = *(const i32x4*)(Bs + rB * 128 + g1 * 16);
      b8[nt] = (i32x8){lo[0], lo[1], lo[2], lo[3], hi[0], hi[1], hi[2], hi[3]};
    }
#pragma unroll
    for (int mt = 0; mt < 4; ++mt)
#pragma unroll
      for (int nt = 0; nt < 4; ++nt)
        acc[mt][nt] = __builtin_amdgcn_mfma_scale_f32_16x16x128_f8f6f4(
            a8[mt], b8[nt], acc[mt][nt], 0, 0,            // cbsz=0 (fp8), blgp=0 (fp8)
            0, 0x7F7F7F7F, 0, 0x7F7F7F7F);                // unity E8M0 scales
  }
#undef ISSUE_PHASE

  // epilogue: masked thresholded sum with symmetry weights
  float local = 0.f;
  int a_base = arow0 + wr * 64;
  int b_base = brow0 + wc * 64;              // 64-aligned
#pragma unroll
  for (int mt = 0; mt < 4; ++mt) {
#pragma unroll
    for (int r = 0; r < 4; ++r) {
      int a = a_base + mt * 16 + quad * 4 + r;
      uint64_t bits = *(const uint64_t*)(adj + (size_t)a * 256 + (b_base >> 5));
#pragma unroll
      for (int nt = 0; nt < 4; ++nt) {
        float v = acc[mt][nt][r];
        int boff = nt * 16 + l15;
        bool conn = (bits >> boff) & 1ull;
        float wgt;
        if (br != bc) wgt = 2.f;
        else {
          int b = b_base + boff;
          wgt = (a < b) ? 2.f : (a == b ? 1.f : 0.f);
        }
        if (!conn && v > THRESH) local += wgt * v;
      }
    }
  }
#pragma unroll
  for (int m = 1; m < 64; m <<= 1) local += __shfl_xor(local, m);
  __syncthreads();                           // done reading LB; reuse as reduction scratch
  float* red = (float*)LB;
  if (lane == 0) red[wv] = local;
  __syncthreads();
  if (t == 0) pp[tb] = red[0] + red[1] + red[2] + red[3];   // NO atomic
}

// ---------- K11: homophily reduce + penalty-partials reduce + combine ----------
__global__ void k_final(const float* __restrict__ scores, const float* __restrict__ deg,
                        const float* __restrict__ pp, float* __restrict__ out) {
  __shared__ float redh[4];
  __shared__ float redp[4];
  int t = threadIdx.x;
  float acch = 0.f;
#pragma unroll 4
  for (int it = 0; it < 32; ++it) {
    int n = it * 256 + t;
    float dg = deg[n];
    acch += scores[n] / (dg == 0.f ? 1.f : dg);
  }
  float accp = 0.f;
#pragma unroll
  for (int it = 0; it < 9; ++it) {
    int idx = it * 256 + t;
    if (idx < 2080) accp += pp[idx];
  }
#pragma unroll
  for (int m = 1; m < 64; m <<= 1) {
    acch += __shfl_xor(acch, m);
    accp += __shfl_xor(accp, m);
  }
  if ((t & 63) == 0) { redh[t >> 6] = acch; redp[t >> 6] = accp; }
  __syncthreads();
  if (t == 0) {
    double h = -(double)(redh[0] + redh[1] + redh[2] + redh[3]) / 8192.0;
    double p = (double)(redp[0] + redp[1] + redp[2] + redp[3]) / (8192.0 * 8192.0);
    out[0] = (float)(h + p);
  }
}

extern "C" void kernel_launch(void* const* d_in, const int* in_sizes, int n_in,
                              void* d_out, int out_size, void* d_ws, size_t ws_size,
                              hipStream_t stream) {
  const float* z = (const float*)d_in[0];
  // d_in[1] = x_hat (unused by the reference)
  const int* ei = (const int*)d_in[2];
  const int* ej = ei + Ee;
  const int* k2u = (const int*)d_in[3];
  const int* u2k = (const int*)d_in[4];

  char* ws = (char*)d_ws;
  // zeroed region: [0, ZERO_BYTES)
  unsigned int* adj = (unsigned int*)(ws);               // 8 MiB
  float* colsum     = (float*)(ws + 8388608);            // 1 KiB
  float* scores     = (float*)(ws + 8389632);            // 32 KiB
  float* deg        = (float*)(ws + 8422400);            // 32 KiB
  const size_t ZERO_BYTES = 8455168;
  // non-zeroed scratch
  float* covp       = (float*)(ws + 8455296);            // 16 x 256 KiB = 4 MiB
  unsigned short* zT  = (unsigned short*)(ws + 12649600); // 4 MiB
  unsigned short* z2b = (unsigned short*)(ws + 16843904); // 4 MiB
  float* cor        = (float*)(ws + 21038208);           // 256 KiB
  float* norms      = (float*)(ws + 21300352);           // 32 KiB
  float* pp         = (float*)(ws + 21333120);           // 2080 floats
  unsigned char* z2f8 = (unsigned char*)(ws + 21341568); // 2 MiB fp8 e4m3

  hipMemsetAsync(d_ws, 0, ZERO_BYTES, stream);
  k_adj<<<1024, 256, 0, stream>>>(ei, ej, adj);
  k_transpose<<<dim3(128, 4), 256, 0, stream>>>(z, zT, colsum);
  k_covg<<<dim3(2, 2, 16), 256, 0, stream>>>(zT, covp);
  k_cor<<<256, 256, 0, stream>>>(covp, colsum, cor);
  k_z2<<<512, 256, 0, stream>>>(z, colsum, k2u, u2k, cor, z2b, z2f8, norms);
  k_edge<<<2048, 256, 0, stream>>>(ei, ej, z2b, norms, scores, deg);
  k_penalty<<<2080, 256, 0, stream>>>(z2f8, adj, pp);
  k_final<<<1, 256, 0, stream>>>(scores, deg, pp, (float*)d_out);
}